// Round 8
// baseline (1767.624 us; speedup 1.0000x reference)
//
#include <hip/hip_runtime.h>
#include <stdint.h>

typedef _Float16 f16;
typedef _Float16 half8 __attribute__((ext_vector_type(8)));
typedef _Float16 half4v __attribute__((ext_vector_type(4)));
typedef float f32x4 __attribute__((ext_vector_type(4)));

#define MFMA16(a,b,c) __builtin_amdgcn_mfma_f32_16x16x32_f16((a),(b),(c),0,0,0)

namespace {

constexpr int BB = 2, SSn = 2048, DDn = 1024, EE = 4, DFF = 4096;
constexpr int MM = BB * SSn;          // 4096 tokens
constexpr int TOPKn = 512;
constexpr int ROWCAP = 8704;          // 8192 token-expert rows + per-expert 128-padding
constexpr float LOSC = 2048.f;        // lo-part storage scale (fp16 denormal safety)
constexpr float LOINV = 1.f / 2048.f;

__device__ __forceinline__ float gelu_f(float x) {
  float z = 0.7978845608028654f * (x + 0.044715f * x * x * x);
  return 0.5f * x * (1.f + tanhf(z));
}

// ---------------- init ----------------
__global__ void k_init(int* __restrict__ rowsl, float* __restrict__ cnt,
                       float* __restrict__ sumP, int* __restrict__ cursor,
                       int* __restrict__ poffs) {
  int i = blockIdx.x * 256 + threadIdx.x;
  if (i < ROWCAP) rowsl[i] = -1;
  if (i < EE) { cnt[i] = 0.f; sumP[i] = 0.f; cursor[i] = 0; }
  if (i < EE + 1) poffs[i] = 0;
}

// ---- transpose f32 sub-block [Rsub x Csub] at (rbase,cbase) -> fp16 [Csub][Rsub] ----
template <bool SPLIT>
__global__ void k_transpose(const float* __restrict__ in, f16* __restrict__ oh,
                            f16* __restrict__ ol, int Rtot, int Ctot, int rbase,
                            int cbase, int Rsub, int Csub) {
  __shared__ float tls[64][65];
  in += (size_t)blockIdx.z * Rtot * Ctot;
  const size_t zo = (size_t)blockIdx.z * Rsub * Csub;
  const int c0 = blockIdx.x * 64, r0 = blockIdx.y * 64;
  const int tc = threadIdx.x & 63, t4 = threadIdx.x >> 6;
#pragma unroll
  for (int p = 0; p < 16; p++) {
    int r = p * 4 + t4;
    float v = 0.f;
    if (r0 + r < Rsub && c0 + tc < Csub)
      v = in[(size_t)(rbase + r0 + r) * Ctot + (cbase + c0 + tc)];
    tls[r][tc] = v;
  }
  __syncthreads();
#pragma unroll
  for (int p = 0; p < 16; p++) {
    int c = p * 4 + t4;
    int r = tc;
    if (c0 + c < Csub && r0 + r < Rsub) {
      float v = tls[r][c];
      f16 hh = (f16)v;
      oh[zo + (size_t)(c0 + c) * Rsub + (r0 + r)] = hh;
      if (SPLIT) ol[zo + (size_t)(c0 + c) * Rsub + (r0 + r)] = (f16)((v - (float)hh) * LOSC);
    }
  }
}

// ---------------- rmsnorm1 -> xn hi/lo ----------------
__global__ void k_rms1(const float* __restrict__ x, const float* __restrict__ w,
                       f16* __restrict__ oh, f16* __restrict__ ol) {
  const int row = blockIdx.x, tid = threadIdx.x;
  const float4 v = ((const float4*)(x + (size_t)row * DDn))[tid];
  float ss = v.x * v.x + v.y * v.y + v.z * v.z + v.w * v.w;
#pragma unroll
  for (int m = 1; m < 64; m <<= 1) ss += __shfl_xor(ss, m);
  __shared__ float wsum[4];
  if ((tid & 63) == 0) wsum[tid >> 6] = ss;
  __syncthreads();
  const float tot = wsum[0] + wsum[1] + wsum[2] + wsum[3];
  const float scale = 1.0f / sqrtf(tot * (1.f / DDn) + 1e-6f);
  const float4 wg = ((const float4*)w)[tid];
  float y[4] = {v.x * scale * wg.x, v.y * scale * wg.y, v.z * scale * wg.z, v.w * scale * wg.w};
  half4v hv, lv;
#pragma unroll
  for (int j = 0; j < 4; j++) {
    f16 h = (f16)y[j];
    hv[j] = h;
    lv[j] = (f16)((y[j] - (float)h) * LOSC);
  }
  *(half4v*)&oh[(size_t)row * DDn + tid * 4] = hv;
  *(half4v*)&ol[(size_t)row * DDn + tid * 4] = lv;
}

// ---------------- generic 128x128 tiled fp16 MFMA GEMM, A[M,K] x Bt[N,K] ----------------
// EPI: 1 = hi/lo out; 2 = f32 (+residual) to two dsts; 3 = gelu(+bias) fp16;
//      4 = (+bias)*wtok atomically into out; 5 = plain f32 out;
//      6 = hi/lo out TRANSPOSED (ldc = leading dim of the transposed output = M-total)
template <bool SPLIT, int EPI, bool GATHER, bool EXPERT>
__global__ __launch_bounds__(256, 2) void k_gemm(
    const f16* __restrict__ Ahi, const f16* __restrict__ Alo, int lda,
    const f16* __restrict__ Bhi, const f16* __restrict__ Blo, int N, int K,
    const int* __restrict__ rowmap, const int* __restrict__ poffs,
    const float* __restrict__ bias, int bstride, const float* __restrict__ xres,
    const float* __restrict__ wtok, f16* __restrict__ co16, f16* __restrict__ co16b,
    float* __restrict__ cof32, float* __restrict__ cof32b, int ldc) {
  constexpr int KT = SPLIT ? 32 : 64;   // K-tile (keeps static LDS <= 64 KiB)
  constexpr int ST = KT + 8;            // padded LDS stride (16B-aligned, conflict-free)
  constexpr int RPI = KT / 8;           // int4 chunks per LDS row
  constexpr int NL = KT / 16;           // int4 loads per thread per array
  __shared__ f16 Ah_s[128 * ST];
  __shared__ f16 Bh_s[128 * ST];
  __shared__ f16 Al_s[SPLIT ? 128 * ST : 8];
  __shared__ f16 Bl_s[SPLIT ? 128 * ST : 8];

  const int tid = threadIdx.x;
  const int row0 = blockIdx.x * 128;
  const int n0 = blockIdx.y * 128;

  if (EXPERT) {
    if (row0 >= poffs[EE]) return;
    int e = 0;
    while (e < EE - 1 && row0 >= poffs[e + 1]) e++;
    Bhi += (size_t)e * N * K;
    if (bias) bias += (size_t)e * bstride;
  }

  const f16* aph[NL];
  const f16* apl[NL];
  const f16* bph[NL];
  const f16* bpl[NL];
  int soff[NL];
#pragma unroll
  for (int i = 0; i < NL; i++) {
    int gid = i * 256 + tid;
    int r = gid / RPI, c = gid % RPI;
    int arow;
    if (GATHER) {
      int rm = rowmap[row0 + r];
      arow = (rm < 0) ? 0 : (rm >> 1);
    } else {
      arow = row0 + r;
    }
    aph[i] = Ahi + (size_t)arow * lda + c * 8;
    if (SPLIT) apl[i] = Alo + (size_t)arow * lda + c * 8;
    int brow = n0 + r;
    if (brow >= N) brow = N - 1;
    bph[i] = Bhi + (size_t)brow * K + c * 8;
    if (SPLIT) bpl[i] = Blo + (size_t)brow * K + c * 8;
    soff[i] = r * ST + c * 8;
  }

  const int lane = tid & 63, wid = tid >> 6;
  const int wr = wid >> 1, wc = wid & 1;
  const int l15 = lane & 15, l4 = lane >> 4;

  f32x4 acc[4][4];
  f32x4 acc2[SPLIT ? 4 : 1][SPLIT ? 4 : 1];
#pragma unroll
  for (int a = 0; a < 4; a++)
#pragma unroll
    for (int b = 0; b < 4; b++) acc[a][b] = (f32x4){0.f, 0.f, 0.f, 0.f};
  if (SPLIT) {
#pragma unroll
    for (int a = 0; a < 4; a++)
#pragma unroll
      for (int b = 0; b < 4; b++) acc2[a][b] = (f32x4){0.f, 0.f, 0.f, 0.f};
  }

  const int nk = K / KT;
  for (int it = 0; it < nk; it++) {
    const int k0 = it * KT;
    __syncthreads();
#pragma unroll
    for (int i = 0; i < NL; i++) {
      *(int4*)&Ah_s[soff[i]] = *(const int4*)(aph[i] + k0);
      *(int4*)&Bh_s[soff[i]] = *(const int4*)(bph[i] + k0);
      if (SPLIT) {
        *(int4*)&Al_s[soff[i]] = *(const int4*)(apl[i] + k0);
        *(int4*)&Bl_s[soff[i]] = *(const int4*)(bpl[i] + k0);
      }
    }
    __syncthreads();
#pragma unroll
    for (int kk = 0; kk < KT / 32; kk++) {
      half8 ah[4], al[4];
#pragma unroll
      for (int mt = 0; mt < 4; mt++) {
        int ro = (wr * 64 + mt * 16 + l15) * ST + kk * 32 + l4 * 8;
        ah[mt] = *(const half8*)&Ah_s[ro];
        if (SPLIT) al[mt] = *(const half8*)&Al_s[ro];
      }
#pragma unroll
      for (int nt = 0; nt < 4; nt++) {
        int ro = (wc * 64 + nt * 16 + l15) * ST + kk * 32 + l4 * 8;
        half8 bh = *(const half8*)&Bh_s[ro];
        if (SPLIT) {
          half8 bl = *(const half8*)&Bl_s[ro];
#pragma unroll
          for (int mt = 0; mt < 4; mt++) {
            acc[mt][nt] = MFMA16(ah[mt], bh, acc[mt][nt]);
            acc2[mt][nt] = MFMA16(ah[mt], bl, acc2[mt][nt]);
            acc2[mt][nt] = MFMA16(al[mt], bh, acc2[mt][nt]);
          }
        } else {
#pragma unroll
          for (int mt = 0; mt < 4; mt++) acc[mt][nt] = MFMA16(ah[mt], bh, acc[mt][nt]);
        }
      }
    }
  }

#pragma unroll
  for (int mt = 0; mt < 4; mt++) {
#pragma unroll
    for (int nt = 0; nt < 4; nt++) {
      if (EPI == 6) {
        // transposed hi/lo store: out[(n0+col)][row] with leading dim ldc (= M-total)
        const int rg0 = row0 + wr * 64 + mt * 16 + l4 * 4;
        const int cg = n0 + wc * 64 + nt * 16 + l15;
        half4v hv, lv;
#pragma unroll
        for (int r = 0; r < 4; r++) {
          float v = acc[mt][nt][r];
          if (SPLIT) v += acc2[mt][nt][r] * LOINV;
          f16 hh = (f16)v;
          hv[r] = hh;
          lv[r] = (f16)((v - (float)hh) * LOSC);
        }
        *(half4v*)&co16[(size_t)cg * ldc + rg0] = hv;
        *(half4v*)&co16b[(size_t)cg * ldc + rg0] = lv;
      } else {
#pragma unroll
        for (int r = 0; r < 4; r++) {
          int rloc = wr * 64 + mt * 16 + l4 * 4 + r;
          int cloc = wc * 64 + nt * 16 + l15;
          int rg = row0 + rloc, cg = n0 + cloc;
          if (cg >= N) continue;
          float v = acc[mt][nt][r];
          if (SPLIT) v += acc2[mt][nt][r] * LOINV;
          if (EPI == 1) {
            f16 h = (f16)v;
            co16[(size_t)rg * ldc + cg] = h;
            co16b[(size_t)rg * ldc + cg] = (f16)((v - (float)h) * LOSC);
          } else if (EPI == 2) {
            size_t o = (size_t)rg * ldc + cg;
            float vv = v + xres[o];
            cof32[o] = vv;
            cof32b[o] = vv;
          } else if (EPI == 3) {
            v += bias[cg];
            co16[(size_t)rg * ldc + cg] = (f16)gelu_f(v);
          } else if (EPI == 4) {
            int rm = rowmap[rg];
            if (rm >= 0) {
              float bb = bias ? bias[cg] : 0.f;
              atomicAdd(&cof32[(size_t)(rm >> 1) * ldc + cg], (v + bb) * wtok[rm]);
            }
          } else if (EPI == 5) {
            cof32[(size_t)rg * ldc + cg] = v;
          }
        }
      }
    }
  }
}

// ------- exact-f32 lightning-indexer scores: 64x64 causal tiles, VALU FMA dots -------
// score[t][s] = sum_h wI[t][h] * relu( sum_d qI[t][h*64+d] * kI[s][d] )  (einsum h-order)
__global__ __launch_bounds__(256, 2) void k_idxf32(const float* __restrict__ qI,
                                                   const float* __restrict__ kI,
                                                   const float* __restrict__ wI,
                                                   float* __restrict__ sc) {
  __shared__ float ks[64][69];
  __shared__ float qs[64][69];
  __shared__ float ws[64][4];
  int xlin = blockIdx.x, ti = 0;
  while (xlin >= ti + 1) { xlin -= ti + 1; ti++; }
  const int si = xlin;
  const int t0 = ti * 64, s0 = si * 64;
  const int b = blockIdx.y;
  const int tid = threadIdx.x;
  {
    int r = tid >> 2, c0 = (tid & 3) * 16;
    const float* src = kI + (size_t)(b * SSn + s0 + r) * 64 + c0;
#pragma unroll
    for (int j = 0; j < 16; j += 4) {
      float4 v = *(const float4*)(src + j);
      ks[r][c0 + j] = v.x; ks[r][c0 + j + 1] = v.y;
      ks[r][c0 + j + 2] = v.z; ks[r][c0 + j + 3] = v.w;
    }
  }
  if (tid < 64) {
    const float* wp = wI + (size_t)(b * SSn + t0 + tid) * 4;
#pragma unroll
    for (int h = 0; h < 4; h++) ws[tid][h] = wp[h];
  }
  const int wv = tid >> 6, lane = tid & 63;
  float sacc[16];
#pragma unroll
  for (int t = 0; t < 16; t++) sacc[t] = 0.f;
  for (int h = 0; h < 4; h++) {
    __syncthreads();
    {
      int r = tid >> 2, c0 = (tid & 3) * 16;
      const float* src = qI + (size_t)(b * SSn + t0 + r) * 256 + h * 64 + c0;
#pragma unroll
      for (int j = 0; j < 16; j += 4) {
        float4 v = *(const float4*)(src + j);
        qs[r][c0 + j] = v.x; qs[r][c0 + j + 1] = v.y;
        qs[r][c0 + j + 2] = v.z; qs[r][c0 + j + 3] = v.w;
      }
    }
    __syncthreads();
#pragma unroll 1
    for (int t = 0; t < 16; t++) {
      const int tr = wv * 16 + t;
      float acc = 0.f;
#pragma unroll
      for (int d = 0; d < 64; d++) acc = fmaf(qs[tr][d], ks[lane][d], acc);
      sacc[t] += ws[tr][h] * fmaxf(acc, 0.f);
    }
  }
#pragma unroll
  for (int t = 0; t < 16; t++) {
    int tt = t0 + wv * 16 + t;
    sc[((size_t)b * SSn + tt) * SSn + (s0 + lane)] = sacc[t];
  }
}

// ---- exact top-512 per row -> bitmask. Rule B: jax.lax.top_k documented semantics —
// ties broken by LOWEST index first; ±0 compare equal (canonicalized). ----
__global__ __launch_bounds__(256) void k_topk(const float* __restrict__ sc,
                                              uint32_t* __restrict__ mw) {
  const int t = blockIdx.x, b = blockIdx.y;
  uint32_t* outw = mw + ((size_t)b * SSn + t) * 64;
  const int tid = threadIdx.x;
  if (t < TOPKn) {  // full causal row (non-causal picks get masked out anyway)
    if (tid < 64) {
      int sbase = tid * 32;
      uint32_t wd;
      if (t >= sbase + 31) wd = 0xFFFFFFFFu;
      else if (t < sbase) wd = 0u;
      else wd = (1u << (t - sbase + 1)) - 1u;
      outw[tid] = wd;
    }
    return;
  }
  __shared__ uint32_t keys[2048];
  __shared__ uint32_t hist[256];
  __shared__ uint32_t scn[256];
  __shared__ uint32_t s_sel, s_krem;
  const float* row = sc + ((size_t)b * SSn + t) * SSn;
  const int n = t + 1;
#pragma unroll
  for (int j = 0; j < 8; j++) {
    int s = tid * 8 + j;
    uint32_t key = 0;
    if (s < n) {
      union { float f; uint32_t u; } cv;
      cv.f = row[s];
      if (cv.f == 0.f) cv.u = 0u;  // canonicalize -0.0 -> +0.0
      key = (cv.u & 0x80000000u) ? ~cv.u : (cv.u | 0x80000000u);
    }
    keys[s] = key;
  }
  uint32_t prefix = 0, krem = TOPKn;
  for (int pass = 3; pass >= 0; pass--) {
    __syncthreads();
    hist[tid] = 0;
    __syncthreads();
    const uint32_t himask = (pass == 3) ? 0u : (0xFFFFFFFFu << (8 * (pass + 1)));
    const int sh = 8 * pass;
#pragma unroll
    for (int j = 0; j < 8; j++) {
      uint32_t key = keys[tid * 8 + j];
      if ((key & himask) == prefix) atomicAdd(&hist[(key >> sh) & 255u], 1u);
    }
    __syncthreads();
    uint32_t v = hist[tid];
    scn[tid] = v;
    __syncthreads();
    for (int o = 1; o < 256; o <<= 1) {
      uint32_t add = (tid + o < 256) ? scn[tid + o] : 0u;
      __syncthreads();
      scn[tid] += add;
      __syncthreads();
    }
    uint32_t inc = scn[tid];
    uint32_t above = inc - v;
    if (inc >= krem && above < krem) { s_sel = (uint32_t)tid; s_krem = krem - above; }
    __syncthreads();
    prefix |= (s_sel << sh);
    krem = s_krem;
  }
  const uint32_t tau = prefix;
  __syncthreads();
  uint32_t kloc[8];
  uint32_t ceq = 0;
#pragma unroll
  for (int j = 0; j < 8; j++) {
    kloc[j] = keys[tid * 8 + j];
    ceq += (kloc[j] == tau) ? 1u : 0u;
  }
  scn[tid] = ceq;
  __syncthreads();
  for (int o = 1; o < 256; o <<= 1) {
    uint32_t add = (tid >= o) ? scn[tid - o] : 0u;
    __syncthreads();
    scn[tid] += add;
    __syncthreads();
  }
  uint32_t rank = scn[tid] - ceq;  // tau-ties strictly before my chunk (index order)
  uint32_t bits = 0;
#pragma unroll
  for (int j = 0; j < 8; j++) {
    bool sel;
    if (kloc[j] > tau) sel = true;
    else if (kloc[j] == tau) { sel = (rank < krem); rank++; }
    else sel = false;
    if (sel) bits |= (1u << j);
  }
  hist[tid] = bits;
  __syncthreads();
  if (tid < 64)
    outw[tid] = hist[tid * 4] | (hist[tid * 4 + 1] << 8) | (hist[tid * 4 + 2] << 16) |
                (hist[tid * 4 + 3] << 24);
}

// ---------------- masked flash attention, full hi/lo split fp16, f32 softmax ----------------
// V in TRANSPOSED global layout vt[d][token] (EPI=6 v-GEMM): LDS stage is a straight b128
// copy.  Next-tile global loads prefetched into named int4 regs (macro; no array, no
// lambda — address-taken regs went to scratch in R2/R3).
// P-scratch: DEDICATED 64x64 swizzled buffers (col' = col ^ (((row>>2)^row)&3)<<4).
// R4-R6 aliased P onto dead Kh/Kl to save LDS, which required a 3rd per-tile barrier
// (all waves must finish QK reads before any P write).  Occupancy is proven capped at
// 2 blocks/CU by VGPR demand (~112; (256,3)/(256,4) bounds spill — R1/R5), so LDS is
// abundant: P gets its own 16 KB and the 3rd barrier is DELETED.  Each wave writes and
// reads only its own 16 P rows — no cross-wave ordering needed.  2 barriers/tile.
// launch_bounds (256,2): REQUIRED (see above).
__global__ __launch_bounds__(256, 2) void k_flash(
    const f16* __restrict__ qh_g, const f16* __restrict__ ql_g, const f16* __restrict__ kh_g,
    const f16* __restrict__ kl_g, const f16* __restrict__ vth_g, const f16* __restrict__ vtl_g,
    const uint32_t* __restrict__ mw, f16* __restrict__ aoh, f16* __restrict__ aol) {
  __shared__ f16 smem[4 * 64 * 72];
  __shared__ f16 Ps[2 * 64 * 64];
  __shared__ uint32_t Msk[64][2];
  f16* Kh = smem;
  f16* Kl = smem + 64 * 72;
  f16* Vh = smem + 2 * 64 * 72;
  f16* Vl = smem + 3 * 64 * 72;
  f16* Psh = Ps;            // [64][64] swizzled, per-wave private rows
  f16* Psl = Ps + 64 * 64;
  const int tid = threadIdx.x, lane = tid & 63, wid = tid >> 6;
  const int l15 = lane & 15, l4 = lane >> 4;
  const int b = blockIdx.y >> 4, h = blockIdx.y & 15;
  const int qi = (int)gridDim.x - 1 - (int)blockIdx.x;   // reversed (neutral, kept)
  const int q0 = qi * 64;
  const int mrl = wid * 16 + l4 * 4;

  half8 qh[2], ql[2];
  {
    const size_t qrow = (size_t)(b * SSn + q0 + wid * 16 + l15) * DDn + h * 64;
#pragma unroll
    for (int kk = 0; kk < 2; kk++) {
      qh[kk] = *(const half8*)(qh_g + qrow + kk * 32 + l4 * 8);
      ql[kk] = *(const half8*)(ql_g + qrow + kk * 32 + l4 * 8);
    }
  }
  float mrow[4], lrow[4];
  f32x4 o1[4], o2[4];
#pragma unroll
  for (int r = 0; r < 4; r++) { mrow[r] = -3e38f; lrow[r] = 0.f; }
#pragma unroll
  for (int d = 0; d < 4; d++) {
    o1[d] = (f32x4){0.f, 0.f, 0.f, 0.f};
    o2[d] = (f32x4){0.f, 0.f, 0.f, 0.f};
  }

  // ---- per-thread staging geometry (rows r0 and r0+32, 16B column chunk cc) ----
  const int r0s = tid >> 3, cc = (tid & 7) * 8;
  const f16* kh_p0 = kh_g + ((size_t)(b * SSn + r0s) * DDn + h * 64 + cc);
  const f16* kl_p0 = kl_g + ((size_t)(b * SSn + r0s) * DDn + h * 64 + cc);
  const f16* kh_p1 = kh_g + ((size_t)(b * SSn + 32 + r0s) * DDn + h * 64 + cc);
  const f16* kl_p1 = kl_g + ((size_t)(b * SSn + 32 + r0s) * DDn + h * 64 + cc);
  const f16* vh_p0 = vth_g + ((size_t)(h * 64 + r0s) * MM + b * SSn + cc);
  const f16* vl_p0 = vtl_g + ((size_t)(h * 64 + r0s) * MM + b * SSn + cc);
  const f16* vh_p1 = vth_g + ((size_t)(h * 64 + 32 + r0s) * MM + b * SSn + cc);
  const f16* vl_p1 = vtl_g + ((size_t)(h * 64 + 32 + r0s) * MM + b * SSn + cc);
  const int soff0 = r0s * 72 + cc;
  const int soff1 = (32 + r0s) * 72 + cc;

  // P read-back swizzle selector for this lane's rows (row = wid*16 + l15)
  const int swq = (((l15 >> 2) ^ l15) & 3) << 4;

  int4 sk0, sl0, sv0, sw0, sk1, sl1, sv1, sw1;   // named regs: never addressable
#define ISSUE_LOADS(ktv)                                            \
  {                                                                 \
    const size_t ko_ = (size_t)(ktv) * 64 * DDn;                    \
    const int vo_ = (ktv) * 64;                                     \
    sk0 = *(const int4*)(kh_p0 + ko_);                              \
    sl0 = *(const int4*)(kl_p0 + ko_);                              \
    sv0 = *(const int4*)(vh_p0 + vo_);                              \
    sw0 = *(const int4*)(vl_p0 + vo_);                              \
    sk1 = *(const int4*)(kh_p1 + ko_);                              \
    sl1 = *(const int4*)(kl_p1 + ko_);                              \
    sv1 = *(const int4*)(vh_p1 + vo_);                              \
    sw1 = *(const int4*)(vl_p1 + vo_);                              \
  }

  ISSUE_LOADS(0)

  for (int kt = 0; kt <= qi; kt++) {
    __syncthreads();  // prev iteration's K (QK) + V (PV) reads all done
    *(int4*)&Kh[soff0] = sk0;
    *(int4*)&Kl[soff0] = sl0;
    *(int4*)&Vh[soff0] = sv0;
    *(int4*)&Vl[soff0] = sw0;
    *(int4*)&Kh[soff1] = sk1;
    *(int4*)&Kl[soff1] = sl1;
    *(int4*)&Vh[soff1] = sv1;
    *(int4*)&Vl[soff1] = sw1;
    if (tid < 128) {
      int r = tid >> 1, w_ = tid & 1;
      Msk[r][w_] = mw[((size_t)b * SSn + q0 + r) * 64 + kt * 2 + w_];
    }
    if (kt < qi) ISSUE_LOADS(kt + 1)  // fly under this tile's compute
    __syncthreads();
    f32x4 s1[4], s2[4];
#pragma unroll
    for (int nt = 0; nt < 4; nt++) {
      s1[nt] = (f32x4){0.f, 0.f, 0.f, 0.f};
      s2[nt] = (f32x4){0.f, 0.f, 0.f, 0.f};
    }
#pragma unroll
    for (int kk = 0; kk < 2; kk++) {
#pragma unroll
      for (int nt = 0; nt < 4; nt++) {
        int ro = (nt * 16 + l15) * 72 + kk * 32 + l4 * 8;
        half8 bh = *(const half8*)&Kh[ro];
        half8 bl = *(const half8*)&Kl[ro];
        s1[nt] = MFMA16(qh[kk], bh, s1[nt]);
        s2[nt] = MFMA16(qh[kk], bl, s2[nt]);
        s2[nt] = MFMA16(ql[kk], bh, s2[nt]);
      }
    }
    float sv_[4][4];
    unsigned okb = 0;
#pragma unroll
    for (int nt = 0; nt < 4; nt++) {
      const int col = nt * 16 + l15;
      const int wsel = col >> 5, bit = col & 31;
#pragma unroll
      for (int r = 0; r < 4; r++) {
        sv_[nt][r] = (s1[nt][r] + s2[nt][r] * LOINV) * 0.125f;
        if ((Msk[mrl + r][wsel] >> bit) & 1u) okb |= 1u << (nt * 4 + r);
      }
    }
    // (no barrier here: P has its own buffer; each wave touches only its own 16 rows)
#pragma unroll
    for (int r = 0; r < 4; r++) {
      float mm = -3e38f;
#pragma unroll
      for (int nt = 0; nt < 4; nt++)
        if (okb & (1u << (nt * 4 + r))) mm = fmaxf(mm, sv_[nt][r]);
#pragma unroll
      for (int o = 1; o < 16; o <<= 1) mm = fmaxf(mm, __shfl_xor(mm, o));
      const float mnew = fmaxf(mrow[r], mm);
      const float alpha = __expf(mrow[r] - mnew);
      float pr[4];
      float psum = 0.f;
#pragma unroll
      for (int nt = 0; nt < 4; nt++) {
        float pp = (okb & (1u << (nt * 4 + r))) ? __expf(sv_[nt][r] - mnew) : 0.f;
        pr[nt] = pp;
        psum += pp;
      }
#pragma unroll
      for (int o = 1; o < 16; o <<= 1) psum += __shfl_xor(psum, o);
      lrow[r] = lrow[r] * alpha + psum;
      mrow[r] = mnew;
#pragma unroll
      for (int d = 0; d < 4; d++) {
        o1[d][r] *= alpha;
        o2[d][r] *= alpha;
      }
      // swizzled P store: row = mrl + r, swz = ((row>>2)^row)&3 = (l4^r)&3
      const int swr = ((l4 ^ r) & 3) << 4;
#pragma unroll
      for (int nt = 0; nt < 4; nt++) {
        f16 ph = (f16)pr[nt];
        const int pcol = (nt * 16 + l15) ^ swr;
        Psh[(mrl + r) * 64 + pcol] = ph;
        Psl[(mrl + r) * 64 + pcol] = (f16)((pr[nt] - (float)ph) * LOSC);
      }
    }
#pragma unroll
    for (int kk = 0; kk < 2; kk++) {
      int po = (wid * 16 + l15) * 64 + ((kk * 32 + l4 * 8) ^ swq);
      half8 aph = *(const half8*)&Psh[po];
      half8 apl = *(const half8*)&Psl[po];
#pragma unroll
      for (int dt = 0; dt < 4; dt++) {
        int rv = (dt * 16 + l15) * 72 + kk * 32 + l4 * 8;
        half8 bh = *(const half8*)&Vh[rv];
        half8 bl = *(const half8*)&Vl[rv];
        o1[dt] = MFMA16(aph, bh, o1[dt]);
        o2[dt] = MFMA16(aph, bl, o2[dt]);
        o2[dt] = MFMA16(apl, bh, o2[dt]);
      }
    }
  }
#undef ISSUE_LOADS
#pragma unroll
  for (int dt = 0; dt < 4; dt++) {
#pragma unroll
    for (int r = 0; r < 4; r++) {
      const int t = q0 + mrl + r;
      const int dcol = dt * 16 + l15;
      const float ov = (o1[dt][r] + o2[dt][r] * LOINV) / lrow[r];
      const size_t o = (size_t)(b * SSn + t) * DDn + h * 64 + dcol;
      f16 hh = (f16)ov;
      aoh[o] = hh;
      aol[o] = (f16)((ov - (float)hh) * LOSC);
    }
  }
}

// ---------------- rmsnorm2 + gate (f32) + top-2 + aux atomics ----------------
__global__ void k_rms2gate(const float* __restrict__ x2, const float* __restrict__ w,
                           const float* __restrict__ gw, f16* __restrict__ oh,
                           int* __restrict__ e01, float* __restrict__ w01,
                           float* __restrict__ cnt, float* __restrict__ sumP) {
  const int row = blockIdx.x, tid = threadIdx.x;
  const float4 v = ((const float4*)(x2 + (size_t)row * DDn))[tid];
  float ss = v.x * v.x + v.y * v.y + v.z * v.z + v.w * v.w;
#pragma unroll
  for (int m = 1; m < 64; m <<= 1) ss += __shfl_xor(ss, m);
  __shared__ float wsum[4];
  if ((tid & 63) == 0) wsum[tid >> 6] = ss;
  __syncthreads();
  const float tot = wsum[0] + wsum[1] + wsum[2] + wsum[3];
  const float scale = 1.0f / sqrtf(tot * (1.f / DDn) + 1e-6f);
  const float4 wg = ((const float4*)w)[tid];
  float y[4] = {v.x * scale * wg.x, v.y * scale * wg.y, v.z * scale * wg.z, v.w * scale * wg.w};
  half4v hv;
#pragma unroll
  for (int j = 0; j < 4; j++) hv[j] = (f16)y[j];
  *(half4v*)&oh[(size_t)row * DDn + tid * 4] = hv;
  float pg[4] = {0.f, 0.f, 0.f, 0.f};
#pragma unroll
  for (int j = 0; j < 4; j++) {
    const float* g = gw + (size_t)(tid * 4 + j) * EE;
#pragma unroll
    for (int e = 0; e < 4; e++) pg[e] += y[j] * g[e];
  }
#pragma unroll
  for (int e = 0; e < 4; e++)
#pragma unroll
    for (int m = 1; m < 64; m <<= 1) pg[e] += __shfl_xor(pg[e], m);
  __shared__ float red[4][4];
  if ((tid & 63) == 0)
#pragma unroll
    for (int e = 0; e < 4; e++) red[tid >> 6][e] = pg[e];
  __syncthreads();
  if (tid == 0) {
    float lg[4];
#pragma unroll
    for (int e = 0; e < 4; e++) lg[e] = red[0][e] + red[1][e] + red[2][e] + red[3][e];
    float mx = fmaxf(fmaxf(lg[0], lg[1]), fmaxf(lg[2], lg[3]));
    float ex[4], sm = 0.f;
#pragma unroll
    for (int e = 0; e < 4; e++) { ex[e] = __expf(lg[e] - mx); sm += ex[e]; }
    float p[4];
#pragma unroll
    for (int e = 0; e < 4; e++) p[e] = ex[e] / sm;
    int e0 = 0;
    for (int e = 1; e < 4; e++) if (p[e] > p[e0]) e0 = e;
    int e1 = -1;
    for (int e = 0; e < 4; e++) {
      if (e == e0) continue;
      if (e1 < 0 || p[e] > p[e1]) e1 = e;
    }
    float t0v = p[e0], t1v = p[e1], ts = t0v + t1v;
    e01[row * 2] = e0;
    e01[row * 2 + 1] = e1;
    w01[row * 2] = t0v / ts;
    w01[row * 2 + 1] = t1v / ts;
    atomicAdd(&cnt[e0], 1.f);
    atomicAdd(&cnt[e1], 1.f);
#pragma unroll
    for (int e = 0; e < 4; e++) atomicAdd(&sumP[e], p[e]);
  }
}

__global__ void k_offsets(const float* __restrict__ cnt, int* __restrict__ poffs,
                          int* __restrict__ cursor) {
  if (threadIdx.x == 0 && blockIdx.x == 0) {
    int off = 0;
    for (int e = 0; e < EE; e++) {
      poffs[e] = off;
      cursor[e] = off;
      int c = (int)(cnt[e] + 0.5f);
      off += (c + 127) & ~127;
    }
    poffs[EE] = off;
  }
}

__global__ void k_scatter(const int* __restrict__ e01, int* __restrict__ cursor,
                          int* __restrict__ rowsl) {
  const int t = blockIdx.x * 256 + threadIdx.x;
  if (t < MM) {
#pragma unroll
    for (int kq = 0; kq < 2; kq++) {
      int e = e01[t * 2 + kq];
      int pos = atomicAdd(&cursor[e], 1);
      rowsl[pos] = t * 2 + kq;
    }
  }
}

__global__ void k_aux(const float* __restrict__ cnt, const float* __restrict__ sumP,
                      float* __restrict__ out) {
  if (threadIdx.x == 0 && blockIdx.x == 0) {
    float a = 0.f;
    for (int e = 0; e < EE; e++) a += (cnt[e] * (1.f / 4096.f)) * (sumP[e] * (1.f / 4096.f));
    out[(size_t)MM * DDn] = (float)EE * a;
  }
}

}  // namespace

extern "C" void kernel_launch(void* const* d_in, const int* in_sizes, int n_in, void* d_out,
                              int out_size, void* d_ws, size_t ws_size, hipStream_t stream) {
  (void)in_sizes; (void)n_in; (void)out_size; (void)ws_size;
  const float* x   = (const float*)d_in[0];
  const float* n1w = (const float*)d_in[1];
  const float* n2w = (const float*)d_in[2];
  const float* wq  = (const float*)d_in[3];
  const float* wk  = (const float*)d_in[4];
  const float* wvp = (const float*)d_in[5];
  const float* wo  = (const float*)d_in[6];
  const float* iwq = (const float*)d_in[7];
  const float* iwk = (const float*)d_in[8];
  const float* iww = (const float*)d_in[9];
  const float* gw  = (const float*)d_in[10];
  const float* w1  = (const float*)d_in[11];
  const float* b1  = (const float*)d_in[12];
  const float* w2  = (const float*)d_in[13];
  const float* b2  = (const float*)d_in[14];
  float* out = (float*)d_out;

  char* base = (char*)d_ws;
  const size_t KB = 1024;
  // ---- small persistent region: [0, 2 MiB) ----
  float* cnt    = (float*)(base + 0);
  float* sumP   = (float*)(base + 256);
  int*   cursor = (int*)(base + 512);
  int*   poffs  = (int*)(base + 768);
  int*   e01    = (int*)(base + 4096);
  float* w01    = (float*)(base + 4096 + 32768);
  int*   rowsl  = (int*)(base + 4096 + 65536);
  uint32_t* mwb = (uint32_t*)(base + 131072);          // 1 MiB
  // ---- x2: [2 MiB, 18 MiB) ----
  float* x2 = (float*)(base + 2048 * KB);
  // ---- arena: [18 MiB, 108 MiB), offsets in KiB ----
  char* arena = base + 18432 * KB;
  auto AK = [&](size_t kib) -> char* { return arena + kib * KB; };
  // phase 1 (attention)
  f16* qfh  = (f16*)AK(0);
  f16* qfl  = (f16*)AK(8192);
  f16* kfh  = (f16*)AK(16384);
  f16* kfl  = (f16*)AK(24576);
  f16* vfh  = (f16*)AK(32768);   // V^T [1024][4096] hi
  f16* vfl  = (f16*)AK(40960);   // V^T [1024][4096] lo
  f16* woTh = (f16*)AK(49152);
  f16* woTl = (f16*)AK(51200);
  float* qIf = (float*)AK(53248);  // [4096][256] f32, 4 MiB
  float* kIf = (float*)AK(57344);  // [4096][64]  f32, 1 MiB
  float* wIf = (float*)AK(58368);  // [4096][4]   f32, 64 KiB
  f16* xn1h = (f16*)AK(59392);   // dies before scb born
  f16* xn1l = (f16*)AK(67584);
  f16* wqTh = (f16*)AK(75776);
  f16* wqTl = (f16*)AK(77824);
  f16* wkTh = (f16*)AK(79872);
  f16* wkTl = (f16*)AK(81920);
  f16* wvTh = (f16*)AK(83968);
  f16* wvTl = (f16*)AK(86016);
  f16* iqTh = (f16*)AK(88064);
  f16* iqTl = (f16*)AK(88576);
  f16* ikTh = (f16*)AK(89088);
  f16* ikTl = (f16*)AK(89216);
  f16* iwTh = (f16*)AK(89344);
  f16* iwTl = (f16*)AK(89352);
  float* scb = (float*)AK(59392);  // 32 MiB, overlays xn1/wT/iT (dead by then)
  f16* aoh = (f16*)AK(59392);      // overlays scb (dead after topk)
  f16* aol = (f16*)AK(67584);
  // phase 2 (MoE) — overlays phase-1 (dead after wo-gemm)
  f16* xn2h = (f16*)AK(0);
  f16* w1Th = (f16*)AK(8192);    // [E][2048][1024], 16 MiB
  f16* w2Th = (f16*)AK(24576);   // [E][1024][2048], 16 MiB
  f16* hbuf = (f16*)AK(40960);   // [8704][2048],    34 MiB

  dim3 blk(256);
  k_init<<<dim3(34), blk, 0, stream>>>(rowsl, cnt, sumP, cursor, poffs);
  k_transpose<true><<<dim3(16, 16), blk, 0, stream>>>(wq,  wqTh, wqTl, 1024, 1024, 0, 0, 1024, 1024);
  k_transpose<true><<<dim3(16, 16), blk, 0, stream>>>(wk,  wkTh, wkTl, 1024, 1024, 0, 0, 1024, 1024);
  k_transpose<true><<<dim3(16, 16), blk, 0, stream>>>(wvp, wvTh, wvTl, 1024, 1024, 0, 0, 1024, 1024);
  k_transpose<true><<<dim3(16, 16), blk, 0, stream>>>(wo,  woTh, woTl, 1024, 1024, 0, 0, 1024, 1024);
  k_transpose<true><<<dim3(4, 16),  blk, 0, stream>>>(iwq, iqTh, iqTl, 1024, 256, 0, 0, 1024, 256);
  k_transpose<true><<<dim3(1, 16),  blk, 0, stream>>>(iwk, ikTh, ikTl, 1024, 64, 0, 0, 1024, 64);
  k_transpose<true><<<dim3(1, 16),  blk, 0, stream>>>(iww, iwTh, iwTl, 1024, 4, 0, 0, 1024, 4);
  k_rms1<<<dim3(MM), blk, 0, stream>>>(x, n1w, xn1h, xn1l);
  k_gemm<true, 1, false, false><<<dim3(32, 8), blk, 0, stream>>>(
      xn1h, xn1l, 1024, wqTh, wqTl, 1024, 1024, nullptr, nullptr, nullptr, 0, nullptr, nullptr,
      qfh, qfl, nullptr, nullptr, 1024);
  k_gemm<true, 1, false, false><<<dim3(32, 8), blk, 0, stream>>>(
      xn1h, xn1l, 1024, wkTh, wkTl, 1024, 1024, nullptr, nullptr, nullptr, 0, nullptr, nullptr,
      kfh, kfl, nullptr, nullptr, 1024);
  k_gemm<true, 6, false, false><<<dim3(32, 8), blk, 0, stream>>>(
      xn1h, xn1l, 1024, wvTh, wvTl, 1024, 1024, nullptr, nullptr, nullptr, 0, nullptr, nullptr,
      vfh, vfl, nullptr, nullptr, MM);
  k_gemm<true, 5, false, false><<<dim3(32, 2), blk, 0, stream>>>(
      xn1h, xn1l, 1024, iqTh, iqTl, 256, 1024, nullptr, nullptr, nullptr, 0, nullptr, nullptr,
      nullptr, nullptr, qIf, nullptr, 256);
  k_gemm<true, 5, false, false><<<dim3(32, 1), blk, 0, stream>>>(
      xn1h, xn1l, 1024, ikTh, ikTl, 64, 1024, nullptr, nullptr, nullptr, 0, nullptr, nullptr,
      nullptr, nullptr, kIf, nullptr, 64);
  k_gemm<true, 5, false, false><<<dim3(32, 1), blk, 0, stream>>>(
      xn1h, xn1l, 1024, iwTh, iwTl, 4, 1024, nullptr, nullptr, nullptr, 0, nullptr, nullptr,
      nullptr, nullptr, wIf, nullptr, 4);
  k_idxf32<<<dim3(528, 2), blk, 0, stream>>>(qIf, kIf, wIf, scb);
  k_topk<<<dim3(SSn, BB), blk, 0, stream>>>(scb, mwb);
  k_flash<<<dim3(32, 32), blk, 0, stream>>>(qfh, qfl, kfh, kfl, vfh, vfl, mwb, aoh, aol);
  k_gemm<true, 2, false, false><<<dim3(32, 8), blk, 0, stream>>>(
      aoh, aol, 1024, woTh, woTl, 1024, 1024, nullptr, nullptr, nullptr, 0, x, nullptr,
      nullptr, nullptr, x2, out, 1024);
  k_rms2gate<<<dim3(MM), blk, 0, stream>>>(x2, n2w, gw, xn2h, e01, w01, cnt, sumP);
  k_offsets<<<dim3(1), dim3(64), 0, stream>>>(cnt, poffs, cursor);
  k_scatter<<<dim3(16), blk, 0, stream>>>(e01, cursor, rowsl);
  k_aux<<<dim3(1), dim3(64), 0, stream>>>(cnt, sumP, out);
  for (int p = 0; p < 2; p++) {
    k_transpose<false><<<dim3(32, 16, 4), blk, 0, stream>>>(
        w1, w1Th, nullptr, 1024, 4096, 0, p * 2048, 1024, 2048);
    k_transpose<false><<<dim3(16, 32, 4), blk, 0, stream>>>(
        w2, w2Th, nullptr, 4096, 1024, p * 2048, 0, 2048, 1024);
    k_gemm<false, 3, true, true><<<dim3(68, 16), blk, 0, stream>>>(
        xn2h, nullptr, 1024, w1Th, nullptr, 2048, 1024, rowsl, poffs, b1 + p * 2048, 4096,
        nullptr, nullptr, hbuf, nullptr, nullptr, nullptr, 2048);
    k_gemm<false, 4, false, true><<<dim3(68, 8), blk, 0, stream>>>(
        hbuf, nullptr, 2048, w2Th, nullptr, 1024, 2048, rowsl, poffs,
        (p == 0) ? b2 : nullptr, 1024, nullptr, w01, nullptr, nullptr, out, nullptr, 1024);
  }
}

// Round 9
// 1690.166 us; speedup vs baseline: 1.0458x; 1.0458x over previous
//
#include <hip/hip_runtime.h>
#include <stdint.h>

typedef _Float16 f16;
typedef _Float16 half8 __attribute__((ext_vector_type(8)));
typedef _Float16 half4v __attribute__((ext_vector_type(4)));
typedef float f32x4 __attribute__((ext_vector_type(4)));

#define MFMA16(a,b,c) __builtin_amdgcn_mfma_f32_16x16x32_f16((a),(b),(c),0,0,0)

namespace {

constexpr int BB = 2, SSn = 2048, DDn = 1024, EE = 4, DFF = 4096;
constexpr int MM = BB * SSn;          // 4096 tokens
constexpr int TOPKn = 512;
constexpr int ROWCAP = 8704;          // 8192 token-expert rows + per-expert 128-padding
constexpr float LOSC = 2048.f;        // lo-part storage scale (fp16 denormal safety)
constexpr float LOINV = 1.f / 2048.f;

__device__ __forceinline__ float gelu_f(float x) {
  float z = 0.7978845608028654f * (x + 0.044715f * x * x * x);
  return 0.5f * x * (1.f + tanhf(z));
}

// ---------------- init ----------------
__global__ void k_init(int* __restrict__ rowsl, float* __restrict__ cnt,
                       float* __restrict__ sumP, int* __restrict__ cursor,
                       int* __restrict__ poffs) {
  int i = blockIdx.x * 256 + threadIdx.x;
  if (i < ROWCAP) rowsl[i] = -1;
  if (i < EE) { cnt[i] = 0.f; sumP[i] = 0.f; cursor[i] = 0; }
  if (i < EE + 1) poffs[i] = 0;
}

// ---- transpose f32 sub-block [Rsub x Csub] at (rbase,cbase) -> fp16 [Csub][Rsub] ----
template <bool SPLIT>
__global__ void k_transpose(const float* __restrict__ in, f16* __restrict__ oh,
                            f16* __restrict__ ol, int Rtot, int Ctot, int rbase,
                            int cbase, int Rsub, int Csub) {
  __shared__ float tls[64][65];
  in += (size_t)blockIdx.z * Rtot * Ctot;
  const size_t zo = (size_t)blockIdx.z * Rsub * Csub;
  const int c0 = blockIdx.x * 64, r0 = blockIdx.y * 64;
  const int tc = threadIdx.x & 63, t4 = threadIdx.x >> 6;
#pragma unroll
  for (int p = 0; p < 16; p++) {
    int r = p * 4 + t4;
    float v = 0.f;
    if (r0 + r < Rsub && c0 + tc < Csub)
      v = in[(size_t)(rbase + r0 + r) * Ctot + (cbase + c0 + tc)];
    tls[r][tc] = v;
  }
  __syncthreads();
#pragma unroll
  for (int p = 0; p < 16; p++) {
    int c = p * 4 + t4;
    int r = tc;
    if (c0 + c < Csub && r0 + r < Rsub) {
      float v = tls[r][c];
      f16 hh = (f16)v;
      oh[zo + (size_t)(c0 + c) * Rsub + (r0 + r)] = hh;
      if (SPLIT) ol[zo + (size_t)(c0 + c) * Rsub + (r0 + r)] = (f16)((v - (float)hh) * LOSC);
    }
  }
}

// ---------------- rmsnorm1 -> xn hi/lo ----------------
__global__ void k_rms1(const float* __restrict__ x, const float* __restrict__ w,
                       f16* __restrict__ oh, f16* __restrict__ ol) {
  const int row = blockIdx.x, tid = threadIdx.x;
  const float4 v = ((const float4*)(x + (size_t)row * DDn))[tid];
  float ss = v.x * v.x + v.y * v.y + v.z * v.z + v.w * v.w;
#pragma unroll
  for (int m = 1; m < 64; m <<= 1) ss += __shfl_xor(ss, m);
  __shared__ float wsum[4];
  if ((tid & 63) == 0) wsum[tid >> 6] = ss;
  __syncthreads();
  const float tot = wsum[0] + wsum[1] + wsum[2] + wsum[3];
  const float scale = 1.0f / sqrtf(tot * (1.f / DDn) + 1e-6f);
  const float4 wg = ((const float4*)w)[tid];
  float y[4] = {v.x * scale * wg.x, v.y * scale * wg.y, v.z * scale * wg.z, v.w * scale * wg.w};
  half4v hv, lv;
#pragma unroll
  for (int j = 0; j < 4; j++) {
    f16 h = (f16)y[j];
    hv[j] = h;
    lv[j] = (f16)((y[j] - (float)h) * LOSC);
  }
  *(half4v*)&oh[(size_t)row * DDn + tid * 4] = hv;
  *(half4v*)&ol[(size_t)row * DDn + tid * 4] = lv;
}

// ---------------- generic 128x128 tiled fp16 MFMA GEMM, A[M,K] x Bt[N,K] ----------------
// EPI: 1 = hi/lo out; 2 = f32 (+residual) to two dsts; 3 = gelu(+bias) fp16;
//      4 = (+bias)*wtok atomically into out; 5 = plain f32 out;
//      6 = hi/lo out TRANSPOSED (ldc = leading dim of the transposed output = M-total)
template <bool SPLIT, int EPI, bool GATHER, bool EXPERT>
__global__ __launch_bounds__(256, 2) void k_gemm(
    const f16* __restrict__ Ahi, const f16* __restrict__ Alo, int lda,
    const f16* __restrict__ Bhi, const f16* __restrict__ Blo, int N, int K,
    const int* __restrict__ rowmap, const int* __restrict__ poffs,
    const float* __restrict__ bias, int bstride, const float* __restrict__ xres,
    const float* __restrict__ wtok, f16* __restrict__ co16, f16* __restrict__ co16b,
    float* __restrict__ cof32, float* __restrict__ cof32b, int ldc) {
  constexpr int KT = SPLIT ? 32 : 64;   // K-tile (keeps static LDS <= 64 KiB)
  constexpr int ST = KT + 8;            // padded LDS stride (16B-aligned, conflict-free)
  constexpr int RPI = KT / 8;           // int4 chunks per LDS row
  constexpr int NL = KT / 16;           // int4 loads per thread per array
  __shared__ f16 Ah_s[128 * ST];
  __shared__ f16 Bh_s[128 * ST];
  __shared__ f16 Al_s[SPLIT ? 128 * ST : 8];
  __shared__ f16 Bl_s[SPLIT ? 128 * ST : 8];

  const int tid = threadIdx.x;
  const int row0 = blockIdx.x * 128;
  const int n0 = blockIdx.y * 128;

  if (EXPERT) {
    if (row0 >= poffs[EE]) return;
    int e = 0;
    while (e < EE - 1 && row0 >= poffs[e + 1]) e++;
    Bhi += (size_t)e * N * K;
    if (bias) bias += (size_t)e * bstride;
  }

  const f16* aph[NL];
  const f16* apl[NL];
  const f16* bph[NL];
  const f16* bpl[NL];
  int soff[NL];
#pragma unroll
  for (int i = 0; i < NL; i++) {
    int gid = i * 256 + tid;
    int r = gid / RPI, c = gid % RPI;
    int arow;
    if (GATHER) {
      int rm = rowmap[row0 + r];
      arow = (rm < 0) ? 0 : (rm >> 1);
    } else {
      arow = row0 + r;
    }
    aph[i] = Ahi + (size_t)arow * lda + c * 8;
    if (SPLIT) apl[i] = Alo + (size_t)arow * lda + c * 8;
    int brow = n0 + r;
    if (brow >= N) brow = N - 1;
    bph[i] = Bhi + (size_t)brow * K + c * 8;
    if (SPLIT) bpl[i] = Blo + (size_t)brow * K + c * 8;
    soff[i] = r * ST + c * 8;
  }

  const int lane = tid & 63, wid = tid >> 6;
  const int wr = wid >> 1, wc = wid & 1;
  const int l15 = lane & 15, l4 = lane >> 4;

  f32x4 acc[4][4];
  f32x4 acc2[SPLIT ? 4 : 1][SPLIT ? 4 : 1];
#pragma unroll
  for (int a = 0; a < 4; a++)
#pragma unroll
    for (int b = 0; b < 4; b++) acc[a][b] = (f32x4){0.f, 0.f, 0.f, 0.f};
  if (SPLIT) {
#pragma unroll
    for (int a = 0; a < 4; a++)
#pragma unroll
      for (int b = 0; b < 4; b++) acc2[a][b] = (f32x4){0.f, 0.f, 0.f, 0.f};
  }

  const int nk = K / KT;
  for (int it = 0; it < nk; it++) {
    const int k0 = it * KT;
    __syncthreads();
#pragma unroll
    for (int i = 0; i < NL; i++) {
      *(int4*)&Ah_s[soff[i]] = *(const int4*)(aph[i] + k0);
      *(int4*)&Bh_s[soff[i]] = *(const int4*)(bph[i] + k0);
      if (SPLIT) {
        *(int4*)&Al_s[soff[i]] = *(const int4*)(apl[i] + k0);
        *(int4*)&Bl_s[soff[i]] = *(const int4*)(bpl[i] + k0);
      }
    }
    __syncthreads();
#pragma unroll
    for (int kk = 0; kk < KT / 32; kk++) {
      half8 ah[4], al[4];
#pragma unroll
      for (int mt = 0; mt < 4; mt++) {
        int ro = (wr * 64 + mt * 16 + l15) * ST + kk * 32 + l4 * 8;
        ah[mt] = *(const half8*)&Ah_s[ro];
        if (SPLIT) al[mt] = *(const half8*)&Al_s[ro];
      }
#pragma unroll
      for (int nt = 0; nt < 4; nt++) {
        int ro = (wc * 64 + nt * 16 + l15) * ST + kk * 32 + l4 * 8;
        half8 bh = *(const half8*)&Bh_s[ro];
        if (SPLIT) {
          half8 bl = *(const half8*)&Bl_s[ro];
#pragma unroll
          for (int mt = 0; mt < 4; mt++) {
            acc[mt][nt] = MFMA16(ah[mt], bh, acc[mt][nt]);
            acc2[mt][nt] = MFMA16(ah[mt], bl, acc2[mt][nt]);
            acc2[mt][nt] = MFMA16(al[mt], bh, acc2[mt][nt]);
          }
        } else {
#pragma unroll
          for (int mt = 0; mt < 4; mt++) acc[mt][nt] = MFMA16(ah[mt], bh, acc[mt][nt]);
        }
      }
    }
  }

#pragma unroll
  for (int mt = 0; mt < 4; mt++) {
#pragma unroll
    for (int nt = 0; nt < 4; nt++) {
      if (EPI == 6) {
        // transposed hi/lo store: out[(n0+col)][row] with leading dim ldc (= M-total)
        const int rg0 = row0 + wr * 64 + mt * 16 + l4 * 4;
        const int cg = n0 + wc * 64 + nt * 16 + l15;
        half4v hv, lv;
#pragma unroll
        for (int r = 0; r < 4; r++) {
          float v = acc[mt][nt][r];
          if (SPLIT) v += acc2[mt][nt][r] * LOINV;
          f16 hh = (f16)v;
          hv[r] = hh;
          lv[r] = (f16)((v - (float)hh) * LOSC);
        }
        *(half4v*)&co16[(size_t)cg * ldc + rg0] = hv;
        *(half4v*)&co16b[(size_t)cg * ldc + rg0] = lv;
      } else {
#pragma unroll
        for (int r = 0; r < 4; r++) {
          int rloc = wr * 64 + mt * 16 + l4 * 4 + r;
          int cloc = wc * 64 + nt * 16 + l15;
          int rg = row0 + rloc, cg = n0 + cloc;
          if (cg >= N) continue;
          float v = acc[mt][nt][r];
          if (SPLIT) v += acc2[mt][nt][r] * LOINV;
          if (EPI == 1) {
            f16 h = (f16)v;
            co16[(size_t)rg * ldc + cg] = h;
            co16b[(size_t)rg * ldc + cg] = (f16)((v - (float)h) * LOSC);
          } else if (EPI == 2) {
            size_t o = (size_t)rg * ldc + cg;
            float vv = v + xres[o];
            cof32[o] = vv;
            cof32b[o] = vv;
          } else if (EPI == 3) {
            v += bias[cg];
            co16[(size_t)rg * ldc + cg] = (f16)gelu_f(v);
          } else if (EPI == 4) {
            int rm = rowmap[rg];
            if (rm >= 0) {
              float bb = bias ? bias[cg] : 0.f;
              atomicAdd(&cof32[(size_t)(rm >> 1) * ldc + cg], (v + bb) * wtok[rm]);
            }
          } else if (EPI == 5) {
            cof32[(size_t)rg * ldc + cg] = v;
          }
        }
      }
    }
  }
}

// ------- exact-f32 lightning-indexer scores: 64x64 causal tiles, VALU FMA dots -------
// score[t][s] = sum_h wI[t][h] * relu( sum_d qI[t][h*64+d] * kI[s][d] )  (einsum h-order)
__global__ __launch_bounds__(256, 2) void k_idxf32(const float* __restrict__ qI,
                                                   const float* __restrict__ kI,
                                                   const float* __restrict__ wI,
                                                   float* __restrict__ sc) {
  __shared__ float ks[64][69];
  __shared__ float qs[64][69];
  __shared__ float ws[64][4];
  int xlin = blockIdx.x, ti = 0;
  while (xlin >= ti + 1) { xlin -= ti + 1; ti++; }
  const int si = xlin;
  const int t0 = ti * 64, s0 = si * 64;
  const int b = blockIdx.y;
  const int tid = threadIdx.x;
  {
    int r = tid >> 2, c0 = (tid & 3) * 16;
    const float* src = kI + (size_t)(b * SSn + s0 + r) * 64 + c0;
#pragma unroll
    for (int j = 0; j < 16; j += 4) {
      float4 v = *(const float4*)(src + j);
      ks[r][c0 + j] = v.x; ks[r][c0 + j + 1] = v.y;
      ks[r][c0 + j + 2] = v.z; ks[r][c0 + j + 3] = v.w;
    }
  }
  if (tid < 64) {
    const float* wp = wI + (size_t)(b * SSn + t0 + tid) * 4;
#pragma unroll
    for (int h = 0; h < 4; h++) ws[tid][h] = wp[h];
  }
  const int wv = tid >> 6, lane = tid & 63;
  float sacc[16];
#pragma unroll
  for (int t = 0; t < 16; t++) sacc[t] = 0.f;
  for (int h = 0; h < 4; h++) {
    __syncthreads();
    {
      int r = tid >> 2, c0 = (tid & 3) * 16;
      const float* src = qI + (size_t)(b * SSn + t0 + r) * 256 + h * 64 + c0;
#pragma unroll
      for (int j = 0; j < 16; j += 4) {
        float4 v = *(const float4*)(src + j);
        qs[r][c0 + j] = v.x; qs[r][c0 + j + 1] = v.y;
        qs[r][c0 + j + 2] = v.z; qs[r][c0 + j + 3] = v.w;
      }
    }
    __syncthreads();
#pragma unroll 1
    for (int t = 0; t < 16; t++) {
      const int tr = wv * 16 + t;
      float acc = 0.f;
#pragma unroll
      for (int d = 0; d < 64; d++) acc = fmaf(qs[tr][d], ks[lane][d], acc);
      sacc[t] += ws[tr][h] * fmaxf(acc, 0.f);
    }
  }
#pragma unroll
  for (int t = 0; t < 16; t++) {
    int tt = t0 + wv * 16 + t;
    sc[((size_t)b * SSn + tt) * SSn + (s0 + lane)] = sacc[t];
  }
}

// ---- exact top-512 per row -> bitmask. Rule B: jax.lax.top_k documented semantics —
// ties broken by LOWEST index first; ±0 compare equal (canonicalized). ----
__global__ __launch_bounds__(256) void k_topk(const float* __restrict__ sc,
                                              uint32_t* __restrict__ mw) {
  const int t = blockIdx.x, b = blockIdx.y;
  uint32_t* outw = mw + ((size_t)b * SSn + t) * 64;
  const int tid = threadIdx.x;
  if (t < TOPKn) {  // full causal row (non-causal picks get masked out anyway)
    if (tid < 64) {
      int sbase = tid * 32;
      uint32_t wd;
      if (t >= sbase + 31) wd = 0xFFFFFFFFu;
      else if (t < sbase) wd = 0u;
      else wd = (1u << (t - sbase + 1)) - 1u;
      outw[tid] = wd;
    }
    return;
  }
  __shared__ uint32_t keys[2048];
  __shared__ uint32_t hist[256];
  __shared__ uint32_t scn[256];
  __shared__ uint32_t s_sel, s_krem;
  const float* row = sc + ((size_t)b * SSn + t) * SSn;
  const int n = t + 1;
#pragma unroll
  for (int j = 0; j < 8; j++) {
    int s = tid * 8 + j;
    uint32_t key = 0;
    if (s < n) {
      union { float f; uint32_t u; } cv;
      cv.f = row[s];
      if (cv.f == 0.f) cv.u = 0u;  // canonicalize -0.0 -> +0.0
      key = (cv.u & 0x80000000u) ? ~cv.u : (cv.u | 0x80000000u);
    }
    keys[s] = key;
  }
  uint32_t prefix = 0, krem = TOPKn;
  for (int pass = 3; pass >= 0; pass--) {
    __syncthreads();
    hist[tid] = 0;
    __syncthreads();
    const uint32_t himask = (pass == 3) ? 0u : (0xFFFFFFFFu << (8 * (pass + 1)));
    const int sh = 8 * pass;
#pragma unroll
    for (int j = 0; j < 8; j++) {
      uint32_t key = keys[tid * 8 + j];
      if ((key & himask) == prefix) atomicAdd(&hist[(key >> sh) & 255u], 1u);
    }
    __syncthreads();
    uint32_t v = hist[tid];
    scn[tid] = v;
    __syncthreads();
    for (int o = 1; o < 256; o <<= 1) {
      uint32_t add = (tid + o < 256) ? scn[tid + o] : 0u;
      __syncthreads();
      scn[tid] += add;
      __syncthreads();
    }
    uint32_t inc = scn[tid];
    uint32_t above = inc - v;
    if (inc >= krem && above < krem) { s_sel = (uint32_t)tid; s_krem = krem - above; }
    __syncthreads();
    prefix |= (s_sel << sh);
    krem = s_krem;
  }
  const uint32_t tau = prefix;
  __syncthreads();
  uint32_t kloc[8];
  uint32_t ceq = 0;
#pragma unroll
  for (int j = 0; j < 8; j++) {
    kloc[j] = keys[tid * 8 + j];
    ceq += (kloc[j] == tau) ? 1u : 0u;
  }
  scn[tid] = ceq;
  __syncthreads();
  for (int o = 1; o < 256; o <<= 1) {
    uint32_t add = (tid >= o) ? scn[tid - o] : 0u;
    __syncthreads();
    scn[tid] += add;
    __syncthreads();
  }
  uint32_t rank = scn[tid] - ceq;  // tau-ties strictly before my chunk (index order)
  uint32_t bits = 0;
#pragma unroll
  for (int j = 0; j < 8; j++) {
    bool sel;
    if (kloc[j] > tau) sel = true;
    else if (kloc[j] == tau) { sel = (rank < krem); rank++; }
    else sel = false;
    if (sel) bits |= (1u << j);
  }
  hist[tid] = bits;
  __syncthreads();
  if (tid < 64)
    outw[tid] = hist[tid * 4] | (hist[tid * 4 + 1] << 8) | (hist[tid * 4 + 2] << 16) |
                (hist[tid * 4 + 3] << 24);
}

// ---------------- masked flash attention, PLAIN fp16 inputs, f32 softmax ----------------
// R9: hi/lo split DROPPED inside flash (was 3x MFMA + 2x staging).  Error budget: fp16
// rounding of Q/K/V/P adds ~6e-3 worst-case to out vs 0.109 threshold (0.031 measured
// baseline from the fp16 MoE path).  Mask/topk come from the exact-f32 indexer path —
// unaffected.  aoh/aol still written as hi/lo of the f32 accumulator (wo-GEMM interface
// unchanged); QKV gemms unchanged (lo outputs simply unread).
// Side effect: LDS 53.8 -> ~27.1 KB and VGPR ~112 -> ~80, so occupancy rises to ~4
// blocks/CU under the SAME (256,2) bound (no allocator squeeze — R1/R5 lesson).
// V in TRANSPOSED global layout vt[d][token] (EPI=6 v-GEMM): straight b128 LDS stage.
// Next-tile loads prefetched into named int4 regs (no array/lambda — R2/R3 scratch).
// P: dedicated 64x64 swizzled buffer (col' = col ^ (((row>>2)^row)&3)<<4), 2 barriers/tile.
__global__ __launch_bounds__(256, 2) void k_flash(
    const f16* __restrict__ qh_g, const f16* __restrict__ ql_g, const f16* __restrict__ kh_g,
    const f16* __restrict__ kl_g, const f16* __restrict__ vth_g, const f16* __restrict__ vtl_g,
    const uint32_t* __restrict__ mw, f16* __restrict__ aoh, f16* __restrict__ aol) {
  __shared__ f16 smem[2 * 64 * 72];
  __shared__ f16 Psh[64 * 64];
  __shared__ uint32_t Msk[64][2];
  f16* Kh = smem;
  f16* Vh = smem + 64 * 72;
  const int tid = threadIdx.x, lane = tid & 63, wid = tid >> 6;
  const int l15 = lane & 15, l4 = lane >> 4;
  const int b = blockIdx.y >> 4, h = blockIdx.y & 15;
  const int qi = (int)gridDim.x - 1 - (int)blockIdx.x;   // reversed (neutral, kept)
  const int q0 = qi * 64;
  const int mrl = wid * 16 + l4 * 4;

  half8 qh[2];
  {
    const size_t qrow = (size_t)(b * SSn + q0 + wid * 16 + l15) * DDn + h * 64;
#pragma unroll
    for (int kk = 0; kk < 2; kk++) {
      qh[kk] = *(const half8*)(qh_g + qrow + kk * 32 + l4 * 8);
    }
  }
  float mrow[4], lrow[4];
  f32x4 o1[4];
#pragma unroll
  for (int r = 0; r < 4; r++) { mrow[r] = -3e38f; lrow[r] = 0.f; }
#pragma unroll
  for (int d = 0; d < 4; d++) o1[d] = (f32x4){0.f, 0.f, 0.f, 0.f};

  // ---- per-thread staging geometry (rows r0 and r0+32, 16B column chunk cc) ----
  const int r0s = tid >> 3, cc = (tid & 7) * 8;
  const f16* kh_p0 = kh_g + ((size_t)(b * SSn + r0s) * DDn + h * 64 + cc);
  const f16* kh_p1 = kh_g + ((size_t)(b * SSn + 32 + r0s) * DDn + h * 64 + cc);
  const f16* vh_p0 = vth_g + ((size_t)(h * 64 + r0s) * MM + b * SSn + cc);
  const f16* vh_p1 = vth_g + ((size_t)(h * 64 + 32 + r0s) * MM + b * SSn + cc);
  const int soff0 = r0s * 72 + cc;
  const int soff1 = (32 + r0s) * 72 + cc;

  // P read-back swizzle selector for this lane's rows (row = wid*16 + l15)
  const int swq = (((l15 >> 2) ^ l15) & 3) << 4;

  int4 sk0, sv0, sk1, sv1;   // named regs: never addressable
#define ISSUE_LOADS(ktv)                                            \
  {                                                                 \
    const size_t ko_ = (size_t)(ktv) * 64 * DDn;                    \
    const int vo_ = (ktv) * 64;                                     \
    sk0 = *(const int4*)(kh_p0 + ko_);                              \
    sv0 = *(const int4*)(vh_p0 + vo_);                              \
    sk1 = *(const int4*)(kh_p1 + ko_);                              \
    sv1 = *(const int4*)(vh_p1 + vo_);                              \
  }

  ISSUE_LOADS(0)

  for (int kt = 0; kt <= qi; kt++) {
    __syncthreads();  // prev iteration's K (QK) + V (PV) reads all done
    *(int4*)&Kh[soff0] = sk0;
    *(int4*)&Vh[soff0] = sv0;
    *(int4*)&Kh[soff1] = sk1;
    *(int4*)&Vh[soff1] = sv1;
    if (tid < 128) {
      int r = tid >> 1, w_ = tid & 1;
      Msk[r][w_] = mw[((size_t)b * SSn + q0 + r) * 64 + kt * 2 + w_];
    }
    if (kt < qi) ISSUE_LOADS(kt + 1)  // fly under this tile's compute
    __syncthreads();
    f32x4 s1[4];
#pragma unroll
    for (int nt = 0; nt < 4; nt++) s1[nt] = (f32x4){0.f, 0.f, 0.f, 0.f};
#pragma unroll
    for (int kk = 0; kk < 2; kk++) {
#pragma unroll
      for (int nt = 0; nt < 4; nt++) {
        int ro = (nt * 16 + l15) * 72 + kk * 32 + l4 * 8;
        half8 bh = *(const half8*)&Kh[ro];
        s1[nt] = MFMA16(qh[kk], bh, s1[nt]);
      }
    }
    float sv_[4][4];
    unsigned okb = 0;
#pragma unroll
    for (int nt = 0; nt < 4; nt++) {
      const int col = nt * 16 + l15;
      const int wsel = col >> 5, bit = col & 31;
#pragma unroll
      for (int r = 0; r < 4; r++) {
        sv_[nt][r] = s1[nt][r] * 0.125f;
        if ((Msk[mrl + r][wsel] >> bit) & 1u) okb |= 1u << (nt * 4 + r);
      }
    }
    // (no barrier here: P has its own buffer; each wave touches only its own 16 rows)
#pragma unroll
    for (int r = 0; r < 4; r++) {
      float mm = -3e38f;
#pragma unroll
      for (int nt = 0; nt < 4; nt++)
        if (okb & (1u << (nt * 4 + r))) mm = fmaxf(mm, sv_[nt][r]);
#pragma unroll
      for (int o = 1; o < 16; o <<= 1) mm = fmaxf(mm, __shfl_xor(mm, o));
      const float mnew = fmaxf(mrow[r], mm);
      const float alpha = __expf(mrow[r] - mnew);
      float pr[4];
      float psum = 0.f;
#pragma unroll
      for (int nt = 0; nt < 4; nt++) {
        float pp = (okb & (1u << (nt * 4 + r))) ? __expf(sv_[nt][r] - mnew) : 0.f;
        pr[nt] = pp;
        psum += pp;
      }
#pragma unroll
      for (int o = 1; o < 16; o <<= 1) psum += __shfl_xor(psum, o);
      lrow[r] = lrow[r] * alpha + psum;
      mrow[r] = mnew;
#pragma unroll
      for (int d = 0; d < 4; d++) o1[d][r] *= alpha;
      // swizzled P store: row = mrl + r, swz = ((row>>2)^row)&3 = (l4^r)&3
      const int swr = ((l4 ^ r) & 3) << 4;
#pragma unroll
      for (int nt = 0; nt < 4; nt++) {
        const int pcol = (nt * 16 + l15) ^ swr;
        Psh[(mrl + r) * 64 + pcol] = (f16)pr[nt];
      }
    }
#pragma unroll
    for (int kk = 0; kk < 2; kk++) {
      int po = (wid * 16 + l15) * 64 + ((kk * 32 + l4 * 8) ^ swq);
      half8 aph = *(const half8*)&Psh[po];
#pragma unroll
      for (int dt = 0; dt < 4; dt++) {
        int rv = (dt * 16 + l15) * 72 + kk * 32 + l4 * 8;
        half8 bh = *(const half8*)&Vh[rv];
        o1[dt] = MFMA16(aph, bh, o1[dt]);
      }
    }
  }
#undef ISSUE_LOADS
#pragma unroll
  for (int dt = 0; dt < 4; dt++) {
#pragma unroll
    for (int r = 0; r < 4; r++) {
      const int t = q0 + mrl + r;
      const int dcol = dt * 16 + l15;
      const float ov = o1[dt][r] / lrow[r];
      const size_t o = (size_t)(b * SSn + t) * DDn + h * 64 + dcol;
      f16 hh = (f16)ov;
      aoh[o] = hh;
      aol[o] = (f16)((ov - (float)hh) * LOSC);
    }
  }
}

// ---------------- rmsnorm2 + gate (f32) + top-2 + aux atomics ----------------
__global__ void k_rms2gate(const float* __restrict__ x2, const float* __restrict__ w,
                           const float* __restrict__ gw, f16* __restrict__ oh,
                           int* __restrict__ e01, float* __restrict__ w01,
                           float* __restrict__ cnt, float* __restrict__ sumP) {
  const int row = blockIdx.x, tid = threadIdx.x;
  const float4 v = ((const float4*)(x2 + (size_t)row * DDn))[tid];
  float ss = v.x * v.x + v.y * v.y + v.z * v.z + v.w * v.w;
#pragma unroll
  for (int m = 1; m < 64; m <<= 1) ss += __shfl_xor(ss, m);
  __shared__ float wsum[4];
  if ((tid & 63) == 0) wsum[tid >> 6] = ss;
  __syncthreads();
  const float tot = wsum[0] + wsum[1] + wsum[2] + wsum[3];
  const float scale = 1.0f / sqrtf(tot * (1.f / DDn) + 1e-6f);
  const float4 wg = ((const float4*)w)[tid];
  float y[4] = {v.x * scale * wg.x, v.y * scale * wg.y, v.z * scale * wg.z, v.w * scale * wg.w};
  half4v hv;
#pragma unroll
  for (int j = 0; j < 4; j++) hv[j] = (f16)y[j];
  *(half4v*)&oh[(size_t)row * DDn + tid * 4] = hv;
  float pg[4] = {0.f, 0.f, 0.f, 0.f};
#pragma unroll
  for (int j = 0; j < 4; j++) {
    const float* g = gw + (size_t)(tid * 4 + j) * EE;
#pragma unroll
    for (int e = 0; e < 4; e++) pg[e] += y[j] * g[e];
  }
#pragma unroll
  for (int e = 0; e < 4; e++)
#pragma unroll
    for (int m = 1; m < 64; m <<= 1) pg[e] += __shfl_xor(pg[e], m);
  __shared__ float red[4][4];
  if ((tid & 63) == 0)
#pragma unroll
    for (int e = 0; e < 4; e++) red[tid >> 6][e] = pg[e];
  __syncthreads();
  if (tid == 0) {
    float lg[4];
#pragma unroll
    for (int e = 0; e < 4; e++) lg[e] = red[0][e] + red[1][e] + red[2][e] + red[3][e];
    float mx = fmaxf(fmaxf(lg[0], lg[1]), fmaxf(lg[2], lg[3]));
    float ex[4], sm = 0.f;
#pragma unroll
    for (int e = 0; e < 4; e++) { ex[e] = __expf(lg[e] - mx); sm += ex[e]; }
    float p[4];
#pragma unroll
    for (int e = 0; e < 4; e++) p[e] = ex[e] / sm;
    int e0 = 0;
    for (int e = 1; e < 4; e++) if (p[e] > p[e0]) e0 = e;
    int e1 = -1;
    for (int e = 0; e < 4; e++) {
      if (e == e0) continue;
      if (e1 < 0 || p[e] > p[e1]) e1 = e;
    }
    float t0v = p[e0], t1v = p[e1], ts = t0v + t1v;
    e01[row * 2] = e0;
    e01[row * 2 + 1] = e1;
    w01[row * 2] = t0v / ts;
    w01[row * 2 + 1] = t1v / ts;
    atomicAdd(&cnt[e0], 1.f);
    atomicAdd(&cnt[e1], 1.f);
#pragma unroll
    for (int e = 0; e < 4; e++) atomicAdd(&sumP[e], p[e]);
  }
}

__global__ void k_offsets(const float* __restrict__ cnt, int* __restrict__ poffs,
                          int* __restrict__ cursor) {
  if (threadIdx.x == 0 && blockIdx.x == 0) {
    int off = 0;
    for (int e = 0; e < EE; e++) {
      poffs[e] = off;
      cursor[e] = off;
      int c = (int)(cnt[e] + 0.5f);
      off += (c + 127) & ~127;
    }
    poffs[EE] = off;
  }
}

__global__ void k_scatter(const int* __restrict__ e01, int* __restrict__ cursor,
                          int* __restrict__ rowsl) {
  const int t = blockIdx.x * 256 + threadIdx.x;
  if (t < MM) {
#pragma unroll
    for (int kq = 0; kq < 2; kq++) {
      int e = e01[t * 2 + kq];
      int pos = atomicAdd(&cursor[e], 1);
      rowsl[pos] = t * 2 + kq;
    }
  }
}

__global__ void k_aux(const float* __restrict__ cnt, const float* __restrict__ sumP,
                      float* __restrict__ out) {
  if (threadIdx.x == 0 && blockIdx.x == 0) {
    float a = 0.f;
    for (int e = 0; e < EE; e++) a += (cnt[e] * (1.f / 4096.f)) * (sumP[e] * (1.f / 4096.f));
    out[(size_t)MM * DDn] = (float)EE * a;
  }
}

}  // namespace

extern "C" void kernel_launch(void* const* d_in, const int* in_sizes, int n_in, void* d_out,
                              int out_size, void* d_ws, size_t ws_size, hipStream_t stream) {
  (void)in_sizes; (void)n_in; (void)out_size; (void)ws_size;
  const float* x   = (const float*)d_in[0];
  const float* n1w = (const float*)d_in[1];
  const float* n2w = (const float*)d_in[2];
  const float* wq  = (const float*)d_in[3];
  const float* wk  = (const float*)d_in[4];
  const float* wvp = (const float*)d_in[5];
  const float* wo  = (const float*)d_in[6];
  const float* iwq = (const float*)d_in[7];
  const float* iwk = (const float*)d_in[8];
  const float* iww = (const float*)d_in[9];
  const float* gw  = (const float*)d_in[10];
  const float* w1  = (const float*)d_in[11];
  const float* b1  = (const float*)d_in[12];
  const float* w2  = (const float*)d_in[13];
  const float* b2  = (const float*)d_in[14];
  float* out = (float*)d_out;

  char* base = (char*)d_ws;
  const size_t KB = 1024;
  // ---- small persistent region: [0, 2 MiB) ----
  float* cnt    = (float*)(base + 0);
  float* sumP   = (float*)(base + 256);
  int*   cursor = (int*)(base + 512);
  int*   poffs  = (int*)(base + 768);
  int*   e01    = (int*)(base + 4096);
  float* w01    = (float*)(base + 4096 + 32768);
  int*   rowsl  = (int*)(base + 4096 + 65536);
  uint32_t* mwb = (uint32_t*)(base + 131072);          // 1 MiB
  // ---- x2: [2 MiB, 18 MiB) ----
  float* x2 = (float*)(base + 2048 * KB);
  // ---- arena: [18 MiB, 108 MiB), offsets in KiB ----
  char* arena = base + 18432 * KB;
  auto AK = [&](size_t kib) -> char* { return arena + kib * KB; };
  // phase 1 (attention)
  f16* qfh  = (f16*)AK(0);
  f16* qfl  = (f16*)AK(8192);
  f16* kfh  = (f16*)AK(16384);
  f16* kfl  = (f16*)AK(24576);
  f16* vfh  = (f16*)AK(32768);   // V^T [1024][4096] hi
  f16* vfl  = (f16*)AK(40960);   // V^T [1024][4096] lo
  f16* woTh = (f16*)AK(49152);
  f16* woTl = (f16*)AK(51200);
  float* qIf = (float*)AK(53248);  // [4096][256] f32, 4 MiB
  float* kIf = (float*)AK(57344);  // [4096][64]  f32, 1 MiB
  float* wIf = (float*)AK(58368);  // [4096][4]   f32, 64 KiB
  f16* xn1h = (f16*)AK(59392);   // dies before scb born
  f16* xn1l = (f16*)AK(67584);
  f16* wqTh = (f16*)AK(75776);
  f16* wqTl = (f16*)AK(77824);
  f16* wkTh = (f16*)AK(79872);
  f16* wkTl = (f16*)AK(81920);
  f16* wvTh = (f16*)AK(83968);
  f16* wvTl = (f16*)AK(86016);
  f16* iqTh = (f16*)AK(88064);
  f16* iqTl = (f16*)AK(88576);
  f16* ikTh = (f16*)AK(89088);
  f16* ikTl = (f16*)AK(89216);
  f16* iwTh = (f16*)AK(89344);
  f16* iwTl = (f16*)AK(89352);
  float* scb = (float*)AK(59392);  // 32 MiB, overlays xn1/wT/iT (dead by then)
  f16* aoh = (f16*)AK(59392);      // overlays scb (dead after topk)
  f16* aol = (f16*)AK(67584);
  // phase 2 (MoE) — overlays phase-1 (dead after wo-gemm)
  f16* xn2h = (f16*)AK(0);
  f16* w1Th = (f16*)AK(8192);    // [E][2048][1024], 16 MiB
  f16* w2Th = (f16*)AK(24576);   // [E][1024][2048], 16 MiB
  f16* hbuf = (f16*)AK(40960);   // [8704][2048],    34 MiB

  dim3 blk(256);
  k_init<<<dim3(34), blk, 0, stream>>>(rowsl, cnt, sumP, cursor, poffs);
  k_transpose<true><<<dim3(16, 16), blk, 0, stream>>>(wq,  wqTh, wqTl, 1024, 1024, 0, 0, 1024, 1024);
  k_transpose<true><<<dim3(16, 16), blk, 0, stream>>>(wk,  wkTh, wkTl, 1024, 1024, 0, 0, 1024, 1024);
  k_transpose<true><<<dim3(16, 16), blk, 0, stream>>>(wvp, wvTh, wvTl, 1024, 1024, 0, 0, 1024, 1024);
  k_transpose<true><<<dim3(16, 16), blk, 0, stream>>>(wo,  woTh, woTl, 1024, 1024, 0, 0, 1024, 1024);
  k_transpose<true><<<dim3(4, 16),  blk, 0, stream>>>(iwq, iqTh, iqTl, 1024, 256, 0, 0, 1024, 256);
  k_transpose<true><<<dim3(1, 16),  blk, 0, stream>>>(iwk, ikTh, ikTl, 1024, 64, 0, 0, 1024, 64);
  k_transpose<true><<<dim3(1, 16),  blk, 0, stream>>>(iww, iwTh, iwTl, 1024, 4, 0, 0, 1024, 4);
  k_rms1<<<dim3(MM), blk, 0, stream>>>(x, n1w, xn1h, xn1l);
  k_gemm<true, 1, false, false><<<dim3(32, 8), blk, 0, stream>>>(
      xn1h, xn1l, 1024, wqTh, wqTl, 1024, 1024, nullptr, nullptr, nullptr, 0, nullptr, nullptr,
      qfh, qfl, nullptr, nullptr, 1024);
  k_gemm<true, 1, false, false><<<dim3(32, 8), blk, 0, stream>>>(
      xn1h, xn1l, 1024, wkTh, wkTl, 1024, 1024, nullptr, nullptr, nullptr, 0, nullptr, nullptr,
      kfh, kfl, nullptr, nullptr, 1024);
  k_gemm<true, 6, false, false><<<dim3(32, 8), blk, 0, stream>>>(
      xn1h, xn1l, 1024, wvTh, wvTl, 1024, 1024, nullptr, nullptr, nullptr, 0, nullptr, nullptr,
      vfh, vfl, nullptr, nullptr, MM);
  k_gemm<true, 5, false, false><<<dim3(32, 2), blk, 0, stream>>>(
      xn1h, xn1l, 1024, iqTh, iqTl, 256, 1024, nullptr, nullptr, nullptr, 0, nullptr, nullptr,
      nullptr, nullptr, qIf, nullptr, 256);
  k_gemm<true, 5, false, false><<<dim3(32, 1), blk, 0, stream>>>(
      xn1h, xn1l, 1024, ikTh, ikTl, 64, 1024, nullptr, nullptr, nullptr, 0, nullptr, nullptr,
      nullptr, nullptr, kIf, nullptr, 64);
  k_gemm<true, 5, false, false><<<dim3(32, 1), blk, 0, stream>>>(
      xn1h, xn1l, 1024, iwTh, iwTl, 4, 1024, nullptr, nullptr, nullptr, 0, nullptr, nullptr,
      nullptr, nullptr, wIf, nullptr, 4);
  k_idxf32<<<dim3(528, 2), blk, 0, stream>>>(qIf, kIf, wIf, scb);
  k_topk<<<dim3(SSn, BB), blk, 0, stream>>>(scb, mwb);
  k_flash<<<dim3(32, 32), blk, 0, stream>>>(qfh, qfl, kfh, kfl, vfh, vfl, mwb, aoh, aol);
  k_gemm<true, 2, false, false><<<dim3(32, 8), blk, 0, stream>>>(
      aoh, aol, 1024, woTh, woTl, 1024, 1024, nullptr, nullptr, nullptr, 0, x, nullptr,
      nullptr, nullptr, x2, out, 1024);
  k_rms2gate<<<dim3(MM), blk, 0, stream>>>(x2, n2w, gw, xn2h, e01, w01, cnt, sumP);
  k_offsets<<<dim3(1), dim3(64), 0, stream>>>(cnt, poffs, cursor);
  k_scatter<<<dim3(16), blk, 0, stream>>>(e01, cursor, rowsl);
  k_aux<<<dim3(1), dim3(64), 0, stream>>>(cnt, sumP, out);
  for (int p = 0; p < 2; p++) {
    k_transpose<false><<<dim3(32, 16, 4), blk, 0, stream>>>(
        w1, w1Th, nullptr, 1024, 4096, 0, p * 2048, 1024, 2048);
    k_transpose<false><<<dim3(16, 32, 4), blk, 0, stream>>>(
        w2, w2Th, nullptr, 4096, 1024, p * 2048, 0, 2048, 1024);
    k_gemm<false, 3, true, true><<<dim3(68, 16), blk, 0, stream>>>(
        xn2h, nullptr, 1024, w1Th, nullptr, 2048, 1024, rowsl, poffs, b1 + p * 2048, 4096,
        nullptr, nullptr, hbuf, nullptr, nullptr, nullptr, 2048);
    k_gemm<false, 4, false, true><<<dim3(68, 8), blk, 0, stream>>>(
        hbuf, nullptr, 2048, w2Th, nullptr, 1024, 2048, rowsl, poffs,
        (p == 0) ? b2 : nullptr, 1024, nullptr, w01, nullptr, nullptr, out, nullptr, 1024);
  }
}

// Round 10
// 1491.058 us; speedup vs baseline: 1.1855x; 1.1335x over previous
//
#include <hip/hip_runtime.h>
#include <stdint.h>

typedef _Float16 f16;
typedef _Float16 half8 __attribute__((ext_vector_type(8)));
typedef _Float16 half4v __attribute__((ext_vector_type(4)));
typedef float f32x4 __attribute__((ext_vector_type(4)));

#define MFMA16(a,b,c) __builtin_amdgcn_mfma_f32_16x16x32_f16((a),(b),(c),0,0,0)

namespace {

constexpr int BB = 2, SSn = 2048, DDn = 1024, EE = 4, DFF = 4096;
constexpr int MM = BB * SSn;          // 4096 tokens
constexpr int TOPKn = 512;
constexpr int ROWCAP = 8704;          // 8192 token-expert rows + per-expert 128-padding
constexpr float LOSC = 2048.f;        // lo-part storage scale (fp16 denormal safety)
constexpr float LOINV = 1.f / 2048.f;

__device__ __forceinline__ float gelu_f(float x) {
  float z = 0.7978845608028654f * (x + 0.044715f * x * x * x);
  return 0.5f * x * (1.f + tanhf(z));
}

// ---------------- init ----------------
__global__ void k_init(int* __restrict__ rowsl, float* __restrict__ cnt,
                       float* __restrict__ sumP, int* __restrict__ cursor,
                       int* __restrict__ poffs) {
  int i = blockIdx.x * 256 + threadIdx.x;
  if (i < ROWCAP) rowsl[i] = -1;
  if (i < EE) { cnt[i] = 0.f; sumP[i] = 0.f; cursor[i] = 0; }
  if (i < EE + 1) poffs[i] = 0;
}

// ---- transpose f32 sub-block [Rsub x Csub] at (rbase,cbase) -> fp16 [Csub][Rsub] ----
template <bool SPLIT>
__global__ void k_transpose(const float* __restrict__ in, f16* __restrict__ oh,
                            f16* __restrict__ ol, int Rtot, int Ctot, int rbase,
                            int cbase, int Rsub, int Csub) {
  __shared__ float tls[64][65];
  in += (size_t)blockIdx.z * Rtot * Ctot;
  const size_t zo = (size_t)blockIdx.z * Rsub * Csub;
  const int c0 = blockIdx.x * 64, r0 = blockIdx.y * 64;
  const int tc = threadIdx.x & 63, t4 = threadIdx.x >> 6;
#pragma unroll
  for (int p = 0; p < 16; p++) {
    int r = p * 4 + t4;
    float v = 0.f;
    if (r0 + r < Rsub && c0 + tc < Csub)
      v = in[(size_t)(rbase + r0 + r) * Ctot + (cbase + c0 + tc)];
    tls[r][tc] = v;
  }
  __syncthreads();
#pragma unroll
  for (int p = 0; p < 16; p++) {
    int c = p * 4 + t4;
    int r = tc;
    if (c0 + c < Csub && r0 + r < Rsub) {
      float v = tls[r][c];
      f16 hh = (f16)v;
      oh[zo + (size_t)(c0 + c) * Rsub + (r0 + r)] = hh;
      if (SPLIT) ol[zo + (size_t)(c0 + c) * Rsub + (r0 + r)] = (f16)((v - (float)hh) * LOSC);
    }
  }
}

// ---------------- rmsnorm1 -> xn hi/lo ----------------
__global__ void k_rms1(const float* __restrict__ x, const float* __restrict__ w,
                       f16* __restrict__ oh, f16* __restrict__ ol) {
  const int row = blockIdx.x, tid = threadIdx.x;
  const float4 v = ((const float4*)(x + (size_t)row * DDn))[tid];
  float ss = v.x * v.x + v.y * v.y + v.z * v.z + v.w * v.w;
#pragma unroll
  for (int m = 1; m < 64; m <<= 1) ss += __shfl_xor(ss, m);
  __shared__ float wsum[4];
  if ((tid & 63) == 0) wsum[tid >> 6] = ss;
  __syncthreads();
  const float tot = wsum[0] + wsum[1] + wsum[2] + wsum[3];
  const float scale = 1.0f / sqrtf(tot * (1.f / DDn) + 1e-6f);
  const float4 wg = ((const float4*)w)[tid];
  float y[4] = {v.x * scale * wg.x, v.y * scale * wg.y, v.z * scale * wg.z, v.w * scale * wg.w};
  half4v hv, lv;
#pragma unroll
  for (int j = 0; j < 4; j++) {
    f16 h = (f16)y[j];
    hv[j] = h;
    lv[j] = (f16)((y[j] - (float)h) * LOSC);
  }
  *(half4v*)&oh[(size_t)row * DDn + tid * 4] = hv;
  *(half4v*)&ol[(size_t)row * DDn + tid * 4] = lv;
}

// ---------------- generic 128x128 tiled fp16 MFMA GEMM, A[M,K] x Bt[N,K] ----------------
// EPI: 1 = hi/lo out; 2 = f32 (+residual) to two dsts; 3 = gelu(+bias) fp16;
//      4 = (+bias)*wtok atomically into out; 5 = plain f32 out;
//      6 = hi/lo out TRANSPOSED (ldc = leading dim of the transposed output = M-total)
template <bool SPLIT, int EPI, bool GATHER, bool EXPERT>
__global__ __launch_bounds__(256, 2) void k_gemm(
    const f16* __restrict__ Ahi, const f16* __restrict__ Alo, int lda,
    const f16* __restrict__ Bhi, const f16* __restrict__ Blo, int N, int K,
    const int* __restrict__ rowmap, const int* __restrict__ poffs,
    const float* __restrict__ bias, int bstride, const float* __restrict__ xres,
    const float* __restrict__ wtok, f16* __restrict__ co16, f16* __restrict__ co16b,
    float* __restrict__ cof32, float* __restrict__ cof32b, int ldc) {
  constexpr int KT = SPLIT ? 32 : 64;   // K-tile (keeps static LDS <= 64 KiB)
  constexpr int ST = KT + 8;            // padded LDS stride (16B-aligned, conflict-free)
  constexpr int RPI = KT / 8;           // int4 chunks per LDS row
  constexpr int NL = KT / 16;           // int4 loads per thread per array
  __shared__ f16 Ah_s[128 * ST];
  __shared__ f16 Bh_s[128 * ST];
  __shared__ f16 Al_s[SPLIT ? 128 * ST : 8];
  __shared__ f16 Bl_s[SPLIT ? 128 * ST : 8];

  const int tid = threadIdx.x;
  const int row0 = blockIdx.x * 128;
  const int n0 = blockIdx.y * 128;

  if (EXPERT) {
    if (row0 >= poffs[EE]) return;
    int e = 0;
    while (e < EE - 1 && row0 >= poffs[e + 1]) e++;
    Bhi += (size_t)e * N * K;
    if (bias) bias += (size_t)e * bstride;
  }

  const f16* aph[NL];
  const f16* apl[NL];
  const f16* bph[NL];
  const f16* bpl[NL];
  int soff[NL];
#pragma unroll
  for (int i = 0; i < NL; i++) {
    int gid = i * 256 + tid;
    int r = gid / RPI, c = gid % RPI;
    int arow;
    if (GATHER) {
      int rm = rowmap[row0 + r];
      arow = (rm < 0) ? 0 : (rm >> 1);
    } else {
      arow = row0 + r;
    }
    aph[i] = Ahi + (size_t)arow * lda + c * 8;
    if (SPLIT) apl[i] = Alo + (size_t)arow * lda + c * 8;
    int brow = n0 + r;
    if (brow >= N) brow = N - 1;
    bph[i] = Bhi + (size_t)brow * K + c * 8;
    if (SPLIT) bpl[i] = Blo + (size_t)brow * K + c * 8;
    soff[i] = r * ST + c * 8;
  }

  const int lane = tid & 63, wid = tid >> 6;
  const int wr = wid >> 1, wc = wid & 1;
  const int l15 = lane & 15, l4 = lane >> 4;

  f32x4 acc[4][4];
  f32x4 acc2[SPLIT ? 4 : 1][SPLIT ? 4 : 1];
#pragma unroll
  for (int a = 0; a < 4; a++)
#pragma unroll
    for (int b = 0; b < 4; b++) acc[a][b] = (f32x4){0.f, 0.f, 0.f, 0.f};
  if (SPLIT) {
#pragma unroll
    for (int a = 0; a < 4; a++)
#pragma unroll
      for (int b = 0; b < 4; b++) acc2[a][b] = (f32x4){0.f, 0.f, 0.f, 0.f};
  }

  const int nk = K / KT;
  for (int it = 0; it < nk; it++) {
    const int k0 = it * KT;
    __syncthreads();
#pragma unroll
    for (int i = 0; i < NL; i++) {
      *(int4*)&Ah_s[soff[i]] = *(const int4*)(aph[i] + k0);
      *(int4*)&Bh_s[soff[i]] = *(const int4*)(bph[i] + k0);
      if (SPLIT) {
        *(int4*)&Al_s[soff[i]] = *(const int4*)(apl[i] + k0);
        *(int4*)&Bl_s[soff[i]] = *(const int4*)(bpl[i] + k0);
      }
    }
    __syncthreads();
#pragma unroll
    for (int kk = 0; kk < KT / 32; kk++) {
      half8 ah[4], al[4];
#pragma unroll
      for (int mt = 0; mt < 4; mt++) {
        int ro = (wr * 64 + mt * 16 + l15) * ST + kk * 32 + l4 * 8;
        ah[mt] = *(const half8*)&Ah_s[ro];
        if (SPLIT) al[mt] = *(const half8*)&Al_s[ro];
      }
#pragma unroll
      for (int nt = 0; nt < 4; nt++) {
        int ro = (wc * 64 + nt * 16 + l15) * ST + kk * 32 + l4 * 8;
        half8 bh = *(const half8*)&Bh_s[ro];
        if (SPLIT) {
          half8 bl = *(const half8*)&Bl_s[ro];
#pragma unroll
          for (int mt = 0; mt < 4; mt++) {
            acc[mt][nt] = MFMA16(ah[mt], bh, acc[mt][nt]);
            acc2[mt][nt] = MFMA16(ah[mt], bl, acc2[mt][nt]);
            acc2[mt][nt] = MFMA16(al[mt], bh, acc2[mt][nt]);
          }
        } else {
#pragma unroll
          for (int mt = 0; mt < 4; mt++) acc[mt][nt] = MFMA16(ah[mt], bh, acc[mt][nt]);
        }
      }
    }
  }

#pragma unroll
  for (int mt = 0; mt < 4; mt++) {
#pragma unroll
    for (int nt = 0; nt < 4; nt++) {
      if (EPI == 6) {
        // transposed hi/lo store: out[(n0+col)][row] with leading dim ldc (= M-total)
        const int rg0 = row0 + wr * 64 + mt * 16 + l4 * 4;
        const int cg = n0 + wc * 64 + nt * 16 + l15;
        half4v hv, lv;
#pragma unroll
        for (int r = 0; r < 4; r++) {
          float v = acc[mt][nt][r];
          if (SPLIT) v += acc2[mt][nt][r] * LOINV;
          f16 hh = (f16)v;
          hv[r] = hh;
          lv[r] = (f16)((v - (float)hh) * LOSC);
        }
        *(half4v*)&co16[(size_t)cg * ldc + rg0] = hv;
        *(half4v*)&co16b[(size_t)cg * ldc + rg0] = lv;
      } else {
#pragma unroll
        for (int r = 0; r < 4; r++) {
          int rloc = wr * 64 + mt * 16 + l4 * 4 + r;
          int cloc = wc * 64 + nt * 16 + l15;
          int rg = row0 + rloc, cg = n0 + cloc;
          if (cg >= N) continue;
          float v = acc[mt][nt][r];
          if (SPLIT) v += acc2[mt][nt][r] * LOINV;
          if (EPI == 1) {
            f16 h = (f16)v;
            co16[(size_t)rg * ldc + cg] = h;
            co16b[(size_t)rg * ldc + cg] = (f16)((v - (float)h) * LOSC);
          } else if (EPI == 2) {
            size_t o = (size_t)rg * ldc + cg;
            float vv = v + xres[o];
            cof32[o] = vv;
            cof32b[o] = vv;
          } else if (EPI == 3) {
            v += bias[cg];
            co16[(size_t)rg * ldc + cg] = (f16)gelu_f(v);
          } else if (EPI == 4) {
            int rm = rowmap[rg];
            if (rm >= 0) {
              float bb = bias ? bias[cg] : 0.f;
              atomicAdd(&cof32[(size_t)(rm >> 1) * ldc + cg], (v + bb) * wtok[rm]);
            }
          } else if (EPI == 5) {
            cof32[(size_t)rg * ldc + cg] = v;
          }
        }
      }
    }
  }
}

// ------- exact-f32 lightning-indexer scores: 64x64 causal tiles, VALU FMA dots -------
// score[t][s] = sum_h wI[t][h] * relu( sum_d qI[t][h*64+d] * kI[s][d] )  (einsum h-order)
__global__ __launch_bounds__(256, 2) void k_idxf32(const float* __restrict__ qI,
                                                   const float* __restrict__ kI,
                                                   const float* __restrict__ wI,
                                                   float* __restrict__ sc) {
  __shared__ float ks[64][69];
  __shared__ float qs[64][69];
  __shared__ float ws[64][4];
  int xlin = blockIdx.x, ti = 0;
  while (xlin >= ti + 1) { xlin -= ti + 1; ti++; }
  const int si = xlin;
  const int t0 = ti * 64, s0 = si * 64;
  const int b = blockIdx.y;
  const int tid = threadIdx.x;
  {
    int r = tid >> 2, c0 = (tid & 3) * 16;
    const float* src = kI + (size_t)(b * SSn + s0 + r) * 64 + c0;
#pragma unroll
    for (int j = 0; j < 16; j += 4) {
      float4 v = *(const float4*)(src + j);
      ks[r][c0 + j] = v.x; ks[r][c0 + j + 1] = v.y;
      ks[r][c0 + j + 2] = v.z; ks[r][c0 + j + 3] = v.w;
    }
  }
  if (tid < 64) {
    const float* wp = wI + (size_t)(b * SSn + t0 + tid) * 4;
#pragma unroll
    for (int h = 0; h < 4; h++) ws[tid][h] = wp[h];
  }
  const int wv = tid >> 6, lane = tid & 63;
  float sacc[16];
#pragma unroll
  for (int t = 0; t < 16; t++) sacc[t] = 0.f;
  for (int h = 0; h < 4; h++) {
    __syncthreads();
    {
      int r = tid >> 2, c0 = (tid & 3) * 16;
      const float* src = qI + (size_t)(b * SSn + t0 + r) * 256 + h * 64 + c0;
#pragma unroll
      for (int j = 0; j < 16; j += 4) {
        float4 v = *(const float4*)(src + j);
        qs[r][c0 + j] = v.x; qs[r][c0 + j + 1] = v.y;
        qs[r][c0 + j + 2] = v.z; qs[r][c0 + j + 3] = v.w;
      }
    }
    __syncthreads();
#pragma unroll 1
    for (int t = 0; t < 16; t++) {
      const int tr = wv * 16 + t;
      float acc = 0.f;
#pragma unroll
      for (int d = 0; d < 64; d++) acc = fmaf(qs[tr][d], ks[lane][d], acc);
      sacc[t] += ws[tr][h] * fmaxf(acc, 0.f);
    }
  }
#pragma unroll
  for (int t = 0; t < 16; t++) {
    int tt = t0 + wv * 16 + t;
    sc[((size_t)b * SSn + tt) * SSn + (s0 + lane)] = sacc[t];
  }
}

// ---- exact top-512 per row -> bitmask. Rule B: jax.lax.top_k documented semantics —
// ties broken by LOWEST index first; ±0 compare equal (canonicalized). ----
__global__ __launch_bounds__(256) void k_topk(const float* __restrict__ sc,
                                              uint32_t* __restrict__ mw) {
  const int t = blockIdx.x, b = blockIdx.y;
  uint32_t* outw = mw + ((size_t)b * SSn + t) * 64;
  const int tid = threadIdx.x;
  if (t < TOPKn) {  // full causal row (non-causal picks get masked out anyway)
    if (tid < 64) {
      int sbase = tid * 32;
      uint32_t wd;
      if (t >= sbase + 31) wd = 0xFFFFFFFFu;
      else if (t < sbase) wd = 0u;
      else wd = (1u << (t - sbase + 1)) - 1u;
      outw[tid] = wd;
    }
    return;
  }
  __shared__ uint32_t keys[2048];
  __shared__ uint32_t hist[256];
  __shared__ uint32_t scn[256];
  __shared__ uint32_t s_sel, s_krem;
  const float* row = sc + ((size_t)b * SSn + t) * SSn;
  const int n = t + 1;
#pragma unroll
  for (int j = 0; j < 8; j++) {
    int s = tid * 8 + j;
    uint32_t key = 0;
    if (s < n) {
      union { float f; uint32_t u; } cv;
      cv.f = row[s];
      if (cv.f == 0.f) cv.u = 0u;  // canonicalize -0.0 -> +0.0
      key = (cv.u & 0x80000000u) ? ~cv.u : (cv.u | 0x80000000u);
    }
    keys[s] = key;
  }
  uint32_t prefix = 0, krem = TOPKn;
  for (int pass = 3; pass >= 0; pass--) {
    __syncthreads();
    hist[tid] = 0;
    __syncthreads();
    const uint32_t himask = (pass == 3) ? 0u : (0xFFFFFFFFu << (8 * (pass + 1)));
    const int sh = 8 * pass;
#pragma unroll
    for (int j = 0; j < 8; j++) {
      uint32_t key = keys[tid * 8 + j];
      if ((key & himask) == prefix) atomicAdd(&hist[(key >> sh) & 255u], 1u);
    }
    __syncthreads();
    uint32_t v = hist[tid];
    scn[tid] = v;
    __syncthreads();
    for (int o = 1; o < 256; o <<= 1) {
      uint32_t add = (tid + o < 256) ? scn[tid + o] : 0u;
      __syncthreads();
      scn[tid] += add;
      __syncthreads();
    }
    uint32_t inc = scn[tid];
    uint32_t above = inc - v;
    if (inc >= krem && above < krem) { s_sel = (uint32_t)tid; s_krem = krem - above; }
    __syncthreads();
    prefix |= (s_sel << sh);
    krem = s_krem;
  }
  const uint32_t tau = prefix;
  __syncthreads();
  uint32_t kloc[8];
  uint32_t ceq = 0;
#pragma unroll
  for (int j = 0; j < 8; j++) {
    kloc[j] = keys[tid * 8 + j];
    ceq += (kloc[j] == tau) ? 1u : 0u;
  }
  scn[tid] = ceq;
  __syncthreads();
  for (int o = 1; o < 256; o <<= 1) {
    uint32_t add = (tid >= o) ? scn[tid - o] : 0u;
    __syncthreads();
    scn[tid] += add;
    __syncthreads();
  }
  uint32_t rank = scn[tid] - ceq;  // tau-ties strictly before my chunk (index order)
  uint32_t bits = 0;
#pragma unroll
  for (int j = 0; j < 8; j++) {
    bool sel;
    if (kloc[j] > tau) sel = true;
    else if (kloc[j] == tau) { sel = (rank < krem); rank++; }
    else sel = false;
    if (sel) bits |= (1u << j);
  }
  hist[tid] = bits;
  __syncthreads();
  if (tid < 64)
    outw[tid] = hist[tid * 4] | (hist[tid * 4 + 1] << 8) | (hist[tid * 4 + 2] << 16) |
                (hist[tid * 4 + 3] << 24);
}

// ---------------- masked flash attention, PLAIN fp16 inputs, f32 softmax ----------------
// R9: hi/lo split dropped inside flash (error budget: ~6e-3 worst vs 0.109 threshold;
// verified R9 absmax 0.03125 unchanged).  aoh/aol still hi/lo of the f32 accumulator.
// V in TRANSPOSED global layout vt[d][token] (EPI=6 v-GEMM): straight b128 LDS stage.
// Next-tile loads prefetched into named int4 regs (no array/lambda — R2/R3 scratch).
// P: dedicated 64x64 swizzled buffer (col' = col ^ (((row>>2)^row)&3)<<4), 2 barriers/tile.
// launch_bounds (256,2): REQUIRED ((256,3)/(256,4) spill — R1/R5).
__global__ __launch_bounds__(256, 2) void k_flash(
    const f16* __restrict__ qh_g, const f16* __restrict__ ql_g, const f16* __restrict__ kh_g,
    const f16* __restrict__ kl_g, const f16* __restrict__ vth_g, const f16* __restrict__ vtl_g,
    const uint32_t* __restrict__ mw, f16* __restrict__ aoh, f16* __restrict__ aol) {
  __shared__ f16 smem[2 * 64 * 72];
  __shared__ f16 Psh[64 * 64];
  __shared__ uint32_t Msk[64][2];
  f16* Kh = smem;
  f16* Vh = smem + 64 * 72;
  const int tid = threadIdx.x, lane = tid & 63, wid = tid >> 6;
  const int l15 = lane & 15, l4 = lane >> 4;
  const int b = blockIdx.y >> 4, h = blockIdx.y & 15;
  const int qi = (int)gridDim.x - 1 - (int)blockIdx.x;   // reversed (neutral, kept)
  const int q0 = qi * 64;
  const int mrl = wid * 16 + l4 * 4;

  half8 qh[2];
  {
    const size_t qrow = (size_t)(b * SSn + q0 + wid * 16 + l15) * DDn + h * 64;
#pragma unroll
    for (int kk = 0; kk < 2; kk++) {
      qh[kk] = *(const half8*)(qh_g + qrow + kk * 32 + l4 * 8);
    }
  }
  float mrow[4], lrow[4];
  f32x4 o1[4];
#pragma unroll
  for (int r = 0; r < 4; r++) { mrow[r] = -3e38f; lrow[r] = 0.f; }
#pragma unroll
  for (int d = 0; d < 4; d++) o1[d] = (f32x4){0.f, 0.f, 0.f, 0.f};

  // ---- per-thread staging geometry (rows r0 and r0+32, 16B column chunk cc) ----
  const int r0s = tid >> 3, cc = (tid & 7) * 8;
  const f16* kh_p0 = kh_g + ((size_t)(b * SSn + r0s) * DDn + h * 64 + cc);
  const f16* kh_p1 = kh_g + ((size_t)(b * SSn + 32 + r0s) * DDn + h * 64 + cc);
  const f16* vh_p0 = vth_g + ((size_t)(h * 64 + r0s) * MM + b * SSn + cc);
  const f16* vh_p1 = vth_g + ((size_t)(h * 64 + 32 + r0s) * MM + b * SSn + cc);
  const int soff0 = r0s * 72 + cc;
  const int soff1 = (32 + r0s) * 72 + cc;

  // P read-back swizzle selector for this lane's rows (row = wid*16 + l15)
  const int swq = (((l15 >> 2) ^ l15) & 3) << 4;

  int4 sk0, sv0, sk1, sv1;   // named regs: never addressable
#define ISSUE_LOADS(ktv)                                            \
  {                                                                 \
    const size_t ko_ = (size_t)(ktv) * 64 * DDn;                    \
    const int vo_ = (ktv) * 64;                                     \
    sk0 = *(const int4*)(kh_p0 + ko_);                              \
    sv0 = *(const int4*)(vh_p0 + vo_);                              \
    sk1 = *(const int4*)(kh_p1 + ko_);                              \
    sv1 = *(const int4*)(vh_p1 + vo_);                              \
  }

  ISSUE_LOADS(0)

  for (int kt = 0; kt <= qi; kt++) {
    __syncthreads();  // prev iteration's K (QK) + V (PV) reads all done
    *(int4*)&Kh[soff0] = sk0;
    *(int4*)&Vh[soff0] = sv0;
    *(int4*)&Kh[soff1] = sk1;
    *(int4*)&Vh[soff1] = sv1;
    if (tid < 128) {
      int r = tid >> 1, w_ = tid & 1;
      Msk[r][w_] = mw[((size_t)b * SSn + q0 + r) * 64 + kt * 2 + w_];
    }
    if (kt < qi) ISSUE_LOADS(kt + 1)  // fly under this tile's compute
    __syncthreads();
    f32x4 s1[4];
#pragma unroll
    for (int nt = 0; nt < 4; nt++) s1[nt] = (f32x4){0.f, 0.f, 0.f, 0.f};
#pragma unroll
    for (int kk = 0; kk < 2; kk++) {
#pragma unroll
      for (int nt = 0; nt < 4; nt++) {
        int ro = (nt * 16 + l15) * 72 + kk * 32 + l4 * 8;
        half8 bh = *(const half8*)&Kh[ro];
        s1[nt] = MFMA16(qh[kk], bh, s1[nt]);
      }
    }
    float sv_[4][4];
    unsigned okb = 0;
#pragma unroll
    for (int nt = 0; nt < 4; nt++) {
      const int col = nt * 16 + l15;
      const int wsel = col >> 5, bit = col & 31;
#pragma unroll
      for (int r = 0; r < 4; r++) {
        sv_[nt][r] = s1[nt][r] * 0.125f;
        if ((Msk[mrl + r][wsel] >> bit) & 1u) okb |= 1u << (nt * 4 + r);
      }
    }
    // (no barrier here: P has its own buffer; each wave touches only its own 16 rows)
#pragma unroll
    for (int r = 0; r < 4; r++) {
      float mm = -3e38f;
#pragma unroll
      for (int nt = 0; nt < 4; nt++)
        if (okb & (1u << (nt * 4 + r))) mm = fmaxf(mm, sv_[nt][r]);
#pragma unroll
      for (int o = 1; o < 16; o <<= 1) mm = fmaxf(mm, __shfl_xor(mm, o));
      const float mnew = fmaxf(mrow[r], mm);
      const float alpha = __expf(mrow[r] - mnew);
      float pr[4];
      float psum = 0.f;
#pragma unroll
      for (int nt = 0; nt < 4; nt++) {
        float pp = (okb & (1u << (nt * 4 + r))) ? __expf(sv_[nt][r] - mnew) : 0.f;
        pr[nt] = pp;
        psum += pp;
      }
#pragma unroll
      for (int o = 1; o < 16; o <<= 1) psum += __shfl_xor(psum, o);
      lrow[r] = lrow[r] * alpha + psum;
      mrow[r] = mnew;
#pragma unroll
      for (int d = 0; d < 4; d++) o1[d][r] *= alpha;
      // swizzled P store: row = mrl + r, swz = ((row>>2)^row)&3 = (l4^r)&3
      const int swr = ((l4 ^ r) & 3) << 4;
#pragma unroll
      for (int nt = 0; nt < 4; nt++) {
        const int pcol = (nt * 16 + l15) ^ swr;
        Psh[(mrl + r) * 64 + pcol] = (f16)pr[nt];
      }
    }
#pragma unroll
    for (int kk = 0; kk < 2; kk++) {
      int po = (wid * 16 + l15) * 64 + ((kk * 32 + l4 * 8) ^ swq);
      half8 aph = *(const half8*)&Psh[po];
#pragma unroll
      for (int dt = 0; dt < 4; dt++) {
        int rv = (dt * 16 + l15) * 72 + kk * 32 + l4 * 8;
        half8 bh = *(const half8*)&Vh[rv];
        o1[dt] = MFMA16(aph, bh, o1[dt]);
      }
    }
  }
#undef ISSUE_LOADS
#pragma unroll
  for (int dt = 0; dt < 4; dt++) {
#pragma unroll
    for (int r = 0; r < 4; r++) {
      const int t = q0 + mrl + r;
      const int dcol = dt * 16 + l15;
      const float ov = o1[dt][r] / lrow[r];
      const size_t o = (size_t)(b * SSn + t) * DDn + h * 64 + dcol;
      f16 hh = (f16)ov;
      aoh[o] = hh;
      aol[o] = (f16)((ov - (float)hh) * LOSC);
    }
  }
}

// ---------------- rmsnorm2 + gate (f32) + top-2; NO ATOMICS ----------------
// R10: the 6 same-address atomicAdds per block (24576 total onto 8 floats) serialized at
// one L2 slice ~= 200us (measured 214us, HBM 1%, VALU 2%).  Replaced by a per-row float4
// store of p[] to pall; cnt/sumP/poffs/cursor are computed by k_gatered (1 block).
__global__ void k_rms2gate(const float* __restrict__ x2, const float* __restrict__ w,
                           const float* __restrict__ gw, f16* __restrict__ oh,
                           int* __restrict__ e01, float* __restrict__ w01,
                           float* __restrict__ pall) {
  const int row = blockIdx.x, tid = threadIdx.x;
  const float4 v = ((const float4*)(x2 + (size_t)row * DDn))[tid];
  float ss = v.x * v.x + v.y * v.y + v.z * v.z + v.w * v.w;
#pragma unroll
  for (int m = 1; m < 64; m <<= 1) ss += __shfl_xor(ss, m);
  __shared__ float wsum[4];
  if ((tid & 63) == 0) wsum[tid >> 6] = ss;
  __syncthreads();
  const float tot = wsum[0] + wsum[1] + wsum[2] + wsum[3];
  const float scale = 1.0f / sqrtf(tot * (1.f / DDn) + 1e-6f);
  const float4 wg = ((const float4*)w)[tid];
  float y[4] = {v.x * scale * wg.x, v.y * scale * wg.y, v.z * scale * wg.z, v.w * scale * wg.w};
  half4v hv;
#pragma unroll
  for (int j = 0; j < 4; j++) hv[j] = (f16)y[j];
  *(half4v*)&oh[(size_t)row * DDn + tid * 4] = hv;
  float pg[4] = {0.f, 0.f, 0.f, 0.f};
#pragma unroll
  for (int j = 0; j < 4; j++) {
    const float* g = gw + (size_t)(tid * 4 + j) * EE;
#pragma unroll
    for (int e = 0; e < 4; e++) pg[e] += y[j] * g[e];
  }
#pragma unroll
  for (int e = 0; e < 4; e++)
#pragma unroll
    for (int m = 1; m < 64; m <<= 1) pg[e] += __shfl_xor(pg[e], m);
  __shared__ float red[4][4];
  if ((tid & 63) == 0)
#pragma unroll
    for (int e = 0; e < 4; e++) red[tid >> 6][e] = pg[e];
  __syncthreads();
  if (tid == 0) {
    float lg[4];
#pragma unroll
    for (int e = 0; e < 4; e++) lg[e] = red[0][e] + red[1][e] + red[2][e] + red[3][e];
    float mx = fmaxf(fmaxf(lg[0], lg[1]), fmaxf(lg[2], lg[3]));
    float ex[4], sm = 0.f;
#pragma unroll
    for (int e = 0; e < 4; e++) { ex[e] = __expf(lg[e] - mx); sm += ex[e]; }
    float p[4];
#pragma unroll
    for (int e = 0; e < 4; e++) p[e] = ex[e] / sm;
    int e0 = 0;
    for (int e = 1; e < 4; e++) if (p[e] > p[e0]) e0 = e;
    int e1 = -1;
    for (int e = 0; e < 4; e++) {
      if (e == e0) continue;
      if (e1 < 0 || p[e] > p[e1]) e1 = e;
    }
    float t0v = p[e0], t1v = p[e1], ts = t0v + t1v;
    e01[row * 2] = e0;
    e01[row * 2 + 1] = e1;
    w01[row * 2] = t0v / ts;
    w01[row * 2 + 1] = t1v / ts;
    float4 pv = {p[0], p[1], p[2], p[3]};
    ((float4*)pall)[row] = pv;
  }
}

// ---- single-block gather-reduce: cnt/sumP from e01/pall, then poffs/cursor scan ----
__global__ void k_gatered(const int* __restrict__ e01, const float* __restrict__ pall,
                          float* __restrict__ cnt, float* __restrict__ sumP,
                          int* __restrict__ poffs, int* __restrict__ cursor) {
  const int tid = threadIdx.x;
  float lc[4] = {0.f, 0.f, 0.f, 0.f};
  float ls[4] = {0.f, 0.f, 0.f, 0.f};
  for (int r = tid; r < MM; r += 256) {
    int a = e01[r * 2], bq = e01[r * 2 + 1];
    lc[a] += 1.f;
    lc[bq] += 1.f;
    float4 p = ((const float4*)pall)[r];
    ls[0] += p.x; ls[1] += p.y; ls[2] += p.z; ls[3] += p.w;
  }
  __shared__ float rc[4][4], rs[4][4];
#pragma unroll
  for (int e = 0; e < 4; e++) {
    float c = lc[e], s = ls[e];
#pragma unroll
    for (int m = 1; m < 64; m <<= 1) { c += __shfl_xor(c, m); s += __shfl_xor(s, m); }
    if ((tid & 63) == 0) { rc[tid >> 6][e] = c; rs[tid >> 6][e] = s; }
  }
  __syncthreads();
  if (tid == 0) {
    int off = 0;
    for (int e = 0; e < EE; e++) {
      float c = rc[0][e] + rc[1][e] + rc[2][e] + rc[3][e];
      float s = rs[0][e] + rs[1][e] + rs[2][e] + rs[3][e];
      cnt[e] = c;
      sumP[e] = s;
      poffs[e] = off;
      cursor[e] = off;
      int ci = (int)(c + 0.5f);
      off += (ci + 127) & ~127;
    }
    poffs[EE] = off;
  }
}

__global__ void k_scatter(const int* __restrict__ e01, int* __restrict__ cursor,
                          int* __restrict__ rowsl) {
  const int t = blockIdx.x * 256 + threadIdx.x;
  if (t < MM) {
#pragma unroll
    for (int kq = 0; kq < 2; kq++) {
      int e = e01[t * 2 + kq];
      int pos = atomicAdd(&cursor[e], 1);
      rowsl[pos] = t * 2 + kq;
    }
  }
}

__global__ void k_aux(const float* __restrict__ cnt, const float* __restrict__ sumP,
                      float* __restrict__ out) {
  if (threadIdx.x == 0 && blockIdx.x == 0) {
    float a = 0.f;
    for (int e = 0; e < EE; e++) a += (cnt[e] * (1.f / 4096.f)) * (sumP[e] * (1.f / 4096.f));
    out[(size_t)MM * DDn] = (float)EE * a;
  }
}

}  // namespace

extern "C" void kernel_launch(void* const* d_in, const int* in_sizes, int n_in, void* d_out,
                              int out_size, void* d_ws, size_t ws_size, hipStream_t stream) {
  (void)in_sizes; (void)n_in; (void)out_size; (void)ws_size;
  const float* x   = (const float*)d_in[0];
  const float* n1w = (const float*)d_in[1];
  const float* n2w = (const float*)d_in[2];
  const float* wq  = (const float*)d_in[3];
  const float* wk  = (const float*)d_in[4];
  const float* wvp = (const float*)d_in[5];
  const float* wo  = (const float*)d_in[6];
  const float* iwq = (const float*)d_in[7];
  const float* iwk = (const float*)d_in[8];
  const float* iww = (const float*)d_in[9];
  const float* gw  = (const float*)d_in[10];
  const float* w1  = (const float*)d_in[11];
  const float* b1  = (const float*)d_in[12];
  const float* w2  = (const float*)d_in[13];
  const float* b2  = (const float*)d_in[14];
  float* out = (float*)d_out;

  char* base = (char*)d_ws;
  const size_t KB = 1024;
  // ---- small persistent region: [0, 2 MiB) ----
  float* cnt    = (float*)(base + 0);
  float* sumP   = (float*)(base + 256);
  int*   cursor = (int*)(base + 512);
  int*   poffs  = (int*)(base + 768);
  int*   e01    = (int*)(base + 4096);
  float* w01    = (float*)(base + 4096 + 32768);
  int*   rowsl  = (int*)(base + 4096 + 65536);
  uint32_t* mwb = (uint32_t*)(base + 131072);          // 1 MiB -> ends at 1152 KiB
  float* pall   = (float*)(base + 1200 * KB);          // [4096][4] f32, 64 KiB
  // ---- x2: [2 MiB, 18 MiB) ----
  float* x2 = (float*)(base + 2048 * KB);
  // ---- arena: [18 MiB, 108 MiB), offsets in KiB ----
  char* arena = base + 18432 * KB;
  auto AK = [&](size_t kib) -> char* { return arena + kib * KB; };
  // phase 1 (attention)
  f16* qfh  = (f16*)AK(0);
  f16* qfl  = (f16*)AK(8192);
  f16* kfh  = (f16*)AK(16384);
  f16* kfl  = (f16*)AK(24576);
  f16* vfh  = (f16*)AK(32768);   // V^T [1024][4096] hi
  f16* vfl  = (f16*)AK(40960);   // V^T [1024][4096] lo
  f16* woTh = (f16*)AK(49152);
  f16* woTl = (f16*)AK(51200);
  float* qIf = (float*)AK(53248);  // [4096][256] f32, 4 MiB
  float* kIf = (float*)AK(57344);  // [4096][64]  f32, 1 MiB
  float* wIf = (float*)AK(58368);  // [4096][4]   f32, 64 KiB
  f16* xn1h = (f16*)AK(59392);   // dies before scb born
  f16* xn1l = (f16*)AK(67584);
  f16* wqTh = (f16*)AK(75776);
  f16* wqTl = (f16*)AK(77824);
  f16* wkTh = (f16*)AK(79872);
  f16* wkTl = (f16*)AK(81920);
  f16* wvTh = (f16*)AK(83968);
  f16* wvTl = (f16*)AK(86016);
  f16* iqTh = (f16*)AK(88064);
  f16* iqTl = (f16*)AK(88576);
  f16* ikTh = (f16*)AK(89088);
  f16* ikTl = (f16*)AK(89216);
  f16* iwTh = (f16*)AK(89344);
  f16* iwTl = (f16*)AK(89352);
  float* scb = (float*)AK(59392);  // 32 MiB, overlays xn1/wT/iT (dead by then)
  f16* aoh = (f16*)AK(59392);      // overlays scb (dead after topk)
  f16* aol = (f16*)AK(67584);
  // phase 2 (MoE) — overlays phase-1 (dead after wo-gemm)
  f16* xn2h = (f16*)AK(0);
  f16* w1Th = (f16*)AK(8192);    // [E][2048][1024], 16 MiB
  f16* w2Th = (f16*)AK(24576);   // [E][1024][2048], 16 MiB
  f16* hbuf = (f16*)AK(40960);   // [8704][2048],    34 MiB

  dim3 blk(256);
  k_init<<<dim3(34), blk, 0, stream>>>(rowsl, cnt, sumP, cursor, poffs);
  k_transpose<true><<<dim3(16, 16), blk, 0, stream>>>(wq,  wqTh, wqTl, 1024, 1024, 0, 0, 1024, 1024);
  k_transpose<true><<<dim3(16, 16), blk, 0, stream>>>(wk,  wkTh, wkTl, 1024, 1024, 0, 0, 1024, 1024);
  k_transpose<true><<<dim3(16, 16), blk, 0, stream>>>(wvp, wvTh, wvTl, 1024, 1024, 0, 0, 1024, 1024);
  k_transpose<true><<<dim3(16, 16), blk, 0, stream>>>(wo,  woTh, woTl, 1024, 1024, 0, 0, 1024, 1024);
  k_transpose<true><<<dim3(4, 16),  blk, 0, stream>>>(iwq, iqTh, iqTl, 1024, 256, 0, 0, 1024, 256);
  k_transpose<true><<<dim3(1, 16),  blk, 0, stream>>>(iwk, ikTh, ikTl, 1024, 64, 0, 0, 1024, 64);
  k_transpose<true><<<dim3(1, 16),  blk, 0, stream>>>(iww, iwTh, iwTl, 1024, 4, 0, 0, 1024, 4);
  k_rms1<<<dim3(MM), blk, 0, stream>>>(x, n1w, xn1h, xn1l);
  k_gemm<true, 1, false, false><<<dim3(32, 8), blk, 0, stream>>>(
      xn1h, xn1l, 1024, wqTh, wqTl, 1024, 1024, nullptr, nullptr, nullptr, 0, nullptr, nullptr,
      qfh, qfl, nullptr, nullptr, 1024);
  k_gemm<true, 1, false, false><<<dim3(32, 8), blk, 0, stream>>>(
      xn1h, xn1l, 1024, wkTh, wkTl, 1024, 1024, nullptr, nullptr, nullptr, 0, nullptr, nullptr,
      kfh, kfl, nullptr, nullptr, 1024);
  k_gemm<true, 6, false, false><<<dim3(32, 8), blk, 0, stream>>>(
      xn1h, xn1l, 1024, wvTh, wvTl, 1024, 1024, nullptr, nullptr, nullptr, 0, nullptr, nullptr,
      vfh, vfl, nullptr, nullptr, MM);
  k_gemm<true, 5, false, false><<<dim3(32, 2), blk, 0, stream>>>(
      xn1h, xn1l, 1024, iqTh, iqTl, 256, 1024, nullptr, nullptr, nullptr, 0, nullptr, nullptr,
      nullptr, nullptr, qIf, nullptr, 256);
  k_gemm<true, 5, false, false><<<dim3(32, 1), blk, 0, stream>>>(
      xn1h, xn1l, 1024, ikTh, ikTl, 64, 1024, nullptr, nullptr, nullptr, 0, nullptr, nullptr,
      nullptr, nullptr, kIf, nullptr, 64);
  k_gemm<true, 5, false, false><<<dim3(32, 1), blk, 0, stream>>>(
      xn1h, xn1l, 1024, iwTh, iwTl, 4, 1024, nullptr, nullptr, nullptr, 0, nullptr, nullptr,
      nullptr, nullptr, wIf, nullptr, 4);
  k_idxf32<<<dim3(528, 2), blk, 0, stream>>>(qIf, kIf, wIf, scb);
  k_topk<<<dim3(SSn, BB), blk, 0, stream>>>(scb, mwb);
  k_flash<<<dim3(32, 32), blk, 0, stream>>>(qfh, qfl, kfh, kfl, vfh, vfl, mwb, aoh, aol);
  k_gemm<true, 2, false, false><<<dim3(32, 8), blk, 0, stream>>>(
      aoh, aol, 1024, woTh, woTl, 1024, 1024, nullptr, nullptr, nullptr, 0, x, nullptr,
      nullptr, nullptr, x2, out, 1024);
  k_rms2gate<<<dim3(MM), blk, 0, stream>>>(x2, n2w, gw, xn2h, e01, w01, pall);
  k_gatered<<<dim3(1), blk, 0, stream>>>(e01, pall, cnt, sumP, poffs, cursor);
  k_scatter<<<dim3(16), blk, 0, stream>>>(e01, cursor, rowsl);
  k_aux<<<dim3(1), dim3(64), 0, stream>>>(cnt, sumP, out);
  for (int p = 0; p < 2; p++) {
    k_transpose<false><<<dim3(32, 16, 4), blk, 0, stream>>>(
        w1, w1Th, nullptr, 1024, 4096, 0, p * 2048, 1024, 2048);
    k_transpose<false><<<dim3(16, 32, 4), blk, 0, stream>>>(
        w2, w2Th, nullptr, 4096, 1024, p * 2048, 0, 2048, 1024);
    k_gemm<false, 3, true, true><<<dim3(68, 16), blk, 0, stream>>>(
        xn2h, nullptr, 1024, w1Th, nullptr, 2048, 1024, rowsl, poffs, b1 + p * 2048, 4096,
        nullptr, nullptr, hbuf, nullptr, nullptr, nullptr, 2048);
    k_gemm<false, 4, false, true><<<dim3(68, 8), blk, 0, stream>>>(
        hbuf, nullptr, 2048, w2Th, nullptr, 1024, 2048, rowsl, poffs,
        (p == 0) ? b2 : nullptr, 1024, nullptr, w01, nullptr, nullptr, out, nullptr, 1024);
  }
}